// Round 1
// 1151.657 us; speedup vs baseline: 1.1899x; 1.1899x over previous
//
#include <hip/hip_runtime.h>
#include <hip/hip_bf16.h>

// ---------------------------------------------------------------------------
// CTCBridgeSparseSlot on MI355X.
// Pipeline:
//   1. prep_w2t   : W2^T = (W_mem @ W_qkv[:,512:1536])^T  -> bf16 [1024][512]
//      bias2      : b2 = b_mem @ Wsub + b_qkv[512:1536]
//   2. cvt_bf16   : proj_feats f32 -> bf16
//   3. kv_gemm    : kv[65536][1024] = proj_bf16 @ W2 + b2  (bf16 MFMA, bf16 out)
//   4. topk_kernel: per (k,b): window-mean scores, exact top-32 (tie=lower idx),
//                   gaussian window weights, gk gate
//   5. z_gather   : Z[768][512] weighted h_ctc window means (f32)
//   6. seed_chain : q = (tanh((Z@Wkv_k + b) @ W_q + b_q)) @ Wqh + bqh (f32)
//   7. attn_kernel: MFMA flash attention (bf16 hi/lo split for Q and P),
//                   blocks = (k,b,h,chunk), 4 waves x 256 keys, in-block merge
//   8. out_chain  : combine partials -> ctx -> @W_attn_out -> @W_o -> *gk -> out
// ---------------------------------------------------------------------------

#define T_LEN 8192
#define DMODEL 512
#define NROWS 768 // 3*8*32

typedef __hip_bfloat16 bf16;
typedef short s16x8 __attribute__((ext_vector_type(8)));
typedef float f32x4 __attribute__((ext_vector_type(4)));
typedef float f4 __attribute__((ext_vector_type(4)));
typedef float f2 __attribute__((ext_vector_type(2)));
typedef int i32x4 __attribute__((ext_vector_type(4)));
typedef struct __attribute__((aligned(16))) { bf16 v[8]; } bf8;

// ---------------- 1. combined weight prep ---------------------------------
// W2[i][j] = sum_l W_mem[i][l] * W_qkv[l][512+j]   (j in [0,1024))
// stored transposed bf16: w2t[j][i]
__global__ __launch_bounds__(256) void prep_w2t(const float* __restrict__ Wmem,
                                                const float* __restrict__ Wqkv,
                                                bf16* __restrict__ w2t) {
  __shared__ __align__(16) float As[16][68]; // As[l][j] = Wqkv[l0+l][512+j0+j]
  __shared__ __align__(16) float Bs[16][68]; // Bs[l][i] = Wmem[i0+i][l0+l]
  int tid = threadIdx.x;
  int j0 = blockIdx.x * 64, i0 = blockIdx.y * 64;
  int ty = tid >> 4, tx = tid & 15;
  float c[4][4];
#pragma unroll
  for (int a = 0; a < 4; a++)
#pragma unroll
    for (int b = 0; b < 4; b++) c[a][b] = 0.f;

  for (int l0 = 0; l0 < 512; l0 += 16) {
    __syncthreads();
    {
      int l = tid >> 4, j4 = (tid & 15) * 4;
      f4 v = *(const f4*)&Wqkv[(size_t)(l0 + l) * 1536 + 512 + j0 + j4];
      *(f4*)&As[l][j4] = v;
    }
    {
      int i = tid >> 2, l4 = (tid & 3) * 4;
      f4 v = *(const f4*)&Wmem[(size_t)(i0 + i) * 512 + l0 + l4];
      Bs[l4 + 0][i] = v[0];
      Bs[l4 + 1][i] = v[1];
      Bs[l4 + 2][i] = v[2];
      Bs[l4 + 3][i] = v[3];
    }
    __syncthreads();
#pragma unroll
    for (int l = 0; l < 16; l++) {
      f4 a = *(f4*)&As[l][ty * 4];
      f4 b = *(f4*)&Bs[l][tx * 4];
#pragma unroll
      for (int jj = 0; jj < 4; jj++)
#pragma unroll
        for (int ii = 0; ii < 4; ii++) c[jj][ii] += a[jj] * b[ii];
    }
  }
#pragma unroll
  for (int jj = 0; jj < 4; jj++)
#pragma unroll
    for (int ii = 0; ii < 4; ii++)
      w2t[(size_t)(j0 + ty * 4 + jj) * 512 + i0 + tx * 4 + ii] =
          __float2bfloat16(c[jj][ii]);
}

__global__ void bias2_kernel(const float* __restrict__ bmem,
                             const float* __restrict__ Wqkv,
                             const float* __restrict__ bqkv,
                             float* __restrict__ b2) {
  int j = blockIdx.x * 256 + threadIdx.x; // [0,1024)
  float acc = bqkv[512 + j];
  for (int l = 0; l < 512; l++) acc += bmem[l] * Wqkv[(size_t)l * 1536 + 512 + j];
  b2[j] = acc;
}

// ---------------- 2. proj -> bf16 -----------------------------------------
__global__ __launch_bounds__(256) void cvt_bf16(const float* __restrict__ x,
                                                bf16* __restrict__ y) {
  int i = blockIdx.x * 256 + threadIdx.x; // 8 elems each, n=33554432
  const f4* p = (const f4*)x;
  f4 a = p[(size_t)i * 2], b = p[(size_t)i * 2 + 1];
  __align__(16) bf16 o[8];
  o[0] = __float2bfloat16(a[0]);
  o[1] = __float2bfloat16(a[1]);
  o[2] = __float2bfloat16(a[2]);
  o[3] = __float2bfloat16(a[3]);
  o[4] = __float2bfloat16(b[0]);
  o[5] = __float2bfloat16(b[1]);
  o[6] = __float2bfloat16(b[2]);
  o[7] = __float2bfloat16(b[3]);
  ((f4*)y)[i] = *(f4*)o;
}

// ---------------- 3. big GEMM: kv = proj_bf16 @ W2 + b2 (bf16 MFMA) -------
// A: [65536][512] bf16 row-major. Bt: [1024][512] bf16 (B transposed).
// C: [65536][1024] bf16. Tile 128x128, BK=32, 4 waves, 4x4 16x16x32 MFMA/wave.
__global__ __launch_bounds__(256) void kv_gemm(const bf16* __restrict__ A,
                                               const bf16* __restrict__ Bt,
                                               const float* __restrict__ bias,
                                               bf16* __restrict__ C) {
  __shared__ __align__(16) bf16 As[128 * 32];
  __shared__ __align__(16) bf16 Bs[128 * 32];
  int tid = threadIdx.x;
  int lane = tid & 63, wave = tid >> 6;
  int wm = wave & 1, wn = wave >> 1;
  int m0 = blockIdx.y * 128, n0 = blockIdx.x * 128;
  int l15 = lane & 15, lq = lane >> 4;
  f32x4 acc[4][4];
#pragma unroll
  for (int mi = 0; mi < 4; mi++)
#pragma unroll
    for (int ni = 0; ni < 4; ni++) acc[mi][ni] = (f32x4){0.f, 0.f, 0.f, 0.f};

  for (int k0 = 0; k0 < 512; k0 += 32) {
    __syncthreads();
#pragma unroll
    for (int t = 0; t < 2; t++) {
      int c = t * 256 + tid;
      int row = c >> 2, kq = c & 3;
      s16x8 av = *(const s16x8*)&A[(size_t)(m0 + row) * 512 + k0 + kq * 8];
      s16x8 bv = *(const s16x8*)&Bt[(size_t)(n0 + row) * 512 + k0 + kq * 8];
      *(s16x8*)&As[c * 8] = av;
      *(s16x8*)&Bs[c * 8] = bv;
    }
    __syncthreads();
    s16x8 af[4], bfr[4];
#pragma unroll
    for (int mi = 0; mi < 4; mi++)
      af[mi] = *(s16x8*)&As[(wm * 64 + mi * 16 + l15) * 32 + lq * 8];
#pragma unroll
    for (int ni = 0; ni < 4; ni++)
      bfr[ni] = *(s16x8*)&Bs[(wn * 64 + ni * 16 + l15) * 32 + lq * 8];
#pragma unroll
    for (int mi = 0; mi < 4; mi++)
#pragma unroll
      for (int ni = 0; ni < 4; ni++)
        acc[mi][ni] = __builtin_amdgcn_mfma_f32_16x16x32_bf16(af[mi], bfr[ni],
                                                              acc[mi][ni], 0, 0, 0);
  }
#pragma unroll
  for (int ni = 0; ni < 4; ni++) {
    int col = n0 + wn * 64 + ni * 16 + l15;
    float bcol = bias[col];
#pragma unroll
    for (int mi = 0; mi < 4; mi++) {
      int row = m0 + wm * 64 + mi * 16 + lq * 4;
      f32x4 v = acc[mi][ni];
#pragma unroll
      for (int r = 0; r < 4; r++)
        C[(size_t)(row + r) * 1024 + col] = __float2bfloat16(v[r] + bcol);
    }
  }
}

// ---------------- 4. top-k spike selection --------------------------------
__global__ __launch_bounds__(128) void topk_kernel(const float* __restrict__ A,
                                                   const int* __restrict__ spikes,
                                                   int* __restrict__ spk_out,
                                                   float* __restrict__ w_out,
                                                   float* __restrict__ winv_out,
                                                   float* __restrict__ gk_out) {
  int kb = blockIdx.x; // (k*8+b) in [0,24)
  int i = threadIdx.x; // [0,128)
  const float* Ab = A + (size_t)kb * T_LEN;
  __shared__ float s_sc[128];
  __shared__ int s_sp[128];
  __shared__ int s_sel[32];
  int t0 = spikes[kb * 128 + i];
  s_sp[i] = t0;
  float sum = 0.f;
  int cnt = 0;
#pragma unroll
  for (int o = -8; o <= 8; o++) {
    int t = t0 + o;
    if (t >= 0 && t < T_LEN) { sum += Ab[t]; cnt++; }
  }
  float sc = (t0 >= 0 && t0 < T_LEN) ? (sum / (float)max(cnt, 1)) : -1e9f;
  s_sc[i] = sc;
  __syncthreads();
  float sci = s_sc[i];
  int rank = 0;
  for (int j = 0; j < 128; j++) {
    float scj = s_sc[j];
    if (scj > sci || (scj == sci && j < i)) rank++;
  }
  if (rank < 32) s_sel[rank] = i;
  __syncthreads();
  if (i < 32) {
    int sel = s_sel[i];
    int spkv = s_sp[sel];
    float conf = s_sc[sel];
    int r = kb * 32 + i;
    spk_out[r] = spkv;
    bool vmask = (spkv >= 0 && spkv < T_LEN);
    float wsum = 0.f;
#pragma unroll
    for (int o = 0; o < 17; o++) {
      int t = spkv + o - 8;
      bool v = vmask && (t >= 0) && (t < T_LEN);
      int tc = min(max(t, 0), T_LEN - 1);
      float off = (float)(o - 8) * 0.25f;
      float g = expf(-0.5f * off * off);
      float wv = v ? g * Ab[tc] : 0.f;
      wsum += wv;
      w_out[r * 17 + o] = wv;
    }
    winv_out[r] = 1.f / (wsum + 1e-6f);
    gk_out[r] = vmask ? (1.f / (1.f + expf(-2.f * conf))) : 0.f;
  }
}

// ---------------- 5. Z gather ---------------------------------------------
__global__ __launch_bounds__(256) void z_gather(const float* __restrict__ hctc,
                                                const int* __restrict__ spk,
                                                const float* __restrict__ warr,
                                                const float* __restrict__ winv,
                                                float* __restrict__ Z) {
  int r = blockIdx.x; // [0,768)
  int tid = threadIdx.x;
  int kb = r >> 5;
  const float* h = hctc + (size_t)kb * T_LEN * DMODEL;
  int sp = spk[r];
  float wi = winv[r];
  float acc0 = 0.f, acc1 = 0.f;
#pragma unroll
  for (int o = 0; o < 17; o++) {
    float wv = warr[r * 17 + o];
    int t = min(max(sp + o - 8, 0), T_LEN - 1);
    const float* hp = h + (size_t)t * DMODEL;
    acc0 += wv * hp[tid];
    acc1 += wv * hp[tid + 256];
  }
  Z[(size_t)r * DMODEL + tid] = acc0 * wi;
  Z[(size_t)r * DMODEL + tid + 256] = acc1 * wi;
}

// ---------------- 6. seed chain: Z -> Kseed -> tanh -> q ------------------
__global__ __launch_bounds__(256) void seed_chain(
    const float* __restrict__ Z, const float* __restrict__ Wkv,
    const float* __restrict__ bkv, const float* __restrict__ Wq,
    const float* __restrict__ bq, const float* __restrict__ Wqkv,
    const float* __restrict__ bqkv, float* __restrict__ qout) {
  __shared__ float Zs[8][512];
  __shared__ float T1[8][512];
  __shared__ float T2[8][512];
  int tid = threadIdx.x;
  int r0 = blockIdx.x * 8;
  int k = r0 >> 8;
  for (int ii = 0; ii < 16; ii++) {
    int idx = tid + ii * 256;
    ((float*)Zs)[idx] = Z[(size_t)r0 * 512 + idx];
  }
  __syncthreads();
  int c0 = tid, c1 = tid + 256;
  { // Kseed = Zs @ Wkv[k][:, :512] + bkv[k][:512]
    const float* W = Wkv + (size_t)k * 512 * 1024;
    float a0[8], a1[8];
#pragma unroll
    for (int i = 0; i < 8; i++) { a0[i] = 0.f; a1[i] = 0.f; }
#pragma unroll 4
    for (int l = 0; l < 512; l++) {
      float w0 = W[(size_t)l * 1024 + c0];
      float w1 = W[(size_t)l * 1024 + c1];
#pragma unroll
      for (int i = 0; i < 8; i++) {
        float z = Zs[i][l];
        a0[i] += z * w0;
        a1[i] += z * w1;
      }
    }
    float bb0 = bkv[k * 1024 + c0], bb1 = bkv[k * 1024 + c1];
#pragma unroll
    for (int i = 0; i < 8; i++) {
      T1[i][c0] = a0[i] + bb0;
      T1[i][c1] = a1[i] + bb1;
    }
  }
  __syncthreads();
  { // T2 = tanh(T1 @ Wq + bq)
    float a0[8], a1[8];
#pragma unroll
    for (int i = 0; i < 8; i++) { a0[i] = 0.f; a1[i] = 0.f; }
#pragma unroll 4
    for (int l = 0; l < 512; l++) {
      float w0 = Wq[(size_t)l * 512 + c0];
      float w1 = Wq[(size_t)l * 512 + c1];
#pragma unroll
      for (int i = 0; i < 8; i++) {
        float z = T1[i][l];
        a0[i] += z * w0;
        a1[i] += z * w1;
      }
    }
    float bb0 = bq[c0], bb1 = bq[c1];
#pragma unroll
    for (int i = 0; i < 8; i++) {
      T2[i][c0] = tanhf(a0[i] + bb0);
      T2[i][c1] = tanhf(a1[i] + bb1);
    }
  }
  __syncthreads();
  { // q = T2 @ Wqkv[:, :512] + bqkv[:512]
    float a0[8], a1[8];
#pragma unroll
    for (int i = 0; i < 8; i++) { a0[i] = 0.f; a1[i] = 0.f; }
#pragma unroll 4
    for (int l = 0; l < 512; l++) {
      float w0 = Wqkv[(size_t)l * 1536 + c0];
      float w1 = Wqkv[(size_t)l * 1536 + c1];
#pragma unroll
      for (int i = 0; i < 8; i++) {
        float z = T2[i][l];
        a0[i] += z * w0;
        a1[i] += z * w1;
      }
    }
    float bb0 = bqkv[c0], bb1 = bqkv[c1];
#pragma unroll
    for (int i = 0; i < 8; i++) {
      qout[(size_t)(r0 + i) * 512 + c0] = a0[i] + bb0;
      qout[(size_t)(r0 + i) * 512 + c1] = a1[i] + bb1;
    }
  }
}

// ---------------- 7. attention (MFMA flash, chunked) ----------------------
// block = (k,b,h,c): 32 queries x 1024 keys, 4 waves x 256 keys each.
// S^T = mfma(K-frag, Q-frag) with 16x16x32 bf16 (same frag convention as
// kv_gemm). Q and P split hi/lo bf16 for ~f32 accuracy. K-frags loaded
// directly from global (no LDS). V transposed per-wave into swizzled LDS.
// P^T frags assembled in-register via ds_bpermute. In-block merge of the
// 4 wave partials -> one pm/pl/pu partial per chunk (out_chain unchanged).

static __device__ __forceinline__ unsigned bf16rne(float f) {
  unsigned x = __builtin_bit_cast(unsigned, f);
  return (x + 0x7fffu + ((x >> 16) & 1u)) >> 16;
}
static __device__ __forceinline__ float bfval(unsigned u) {
  return __builtin_bit_cast(float, u << 16);
}
static __device__ __forceinline__ void hilo(float x, unsigned& h, unsigned& l) {
  h = bf16rne(x);
  l = bf16rne(x - bfval(h));
}

__global__ __launch_bounds__(256) void attn_kernel(const bf16* __restrict__ kv,
                                                   const float* __restrict__ qws,
                                                   float* __restrict__ pm,
                                                   float* __restrict__ pl,
                                                   float* __restrict__ pu) {
  // per-wave V^T tile, swizzled: elem (d,t) at d*32 + (t&7) + (((t>>3)^((d>>3)&3))<<3)
  __shared__ short Vts[4][2048];
  __shared__ float ctxc[4][32][68]; // per-wave ctx for combine (padded rows)
  __shared__ float cm[4][32];
  __shared__ float cl[4][32];

  int tid = threadIdx.x;
  int w = tid >> 6, lane = tid & 63;
  int l15 = lane & 15, g = lane >> 4;
  int bx = blockIdx.x;
  int c = bx & 7, h = (bx >> 3) & 7, b = (bx >> 6) & 7, k = bx >> 9;
  int kb = k * 8 + b;
  const short* kvS = (const short*)kv;
  int hoff = h * 64;
  int rowK = b * T_LEN + c * 1024 + w * 256;

  // ---- Q hoist: B-frags [qtile][dslice][hi/lo], scaled by 1/sqrt(64)
  s16x8 qf[2][2][2];
#pragma unroll
  for (int qt = 0; qt < 2; qt++)
#pragma unroll
    for (int ds = 0; ds < 2; ds++) {
      const float* qp =
          qws + (size_t)(kb * 32 + qt * 16 + l15) * 512 + hoff + ds * 32 + g * 8;
      f4 x = *(const f4*)qp;
      f4 y = *(const f4*)(qp + 4);
      x *= 0.125f;
      y *= 0.125f;
      s16x8 hi, lo;
#pragma unroll
      for (int j = 0; j < 4; j++) {
        unsigned hb, lb;
        hilo(x[j], hb, lb);
        hi[j] = (short)hb;
        lo[j] = (short)lb;
        hilo(y[j], hb, lb);
        hi[4 + j] = (short)hb;
        lo[4 + j] = (short)lb;
      }
      qf[qt][ds][0] = hi;
      qf[qt][ds][1] = lo;
    }

  float mq[2] = {-3.0e38f, -3.0e38f};
  float lq[2] = {0.f, 0.f};
  f32x4 ctx[4][2]; // [dtile][qtile], ctx^T: row d = dt*16+g*4+r, col q = qt*16+l15
#pragma unroll
  for (int dt = 0; dt < 4; dt++)
#pragma unroll
    for (int qt = 0; qt < 2; qt++) ctx[dt][qt] = (f32x4){0.f, 0.f, 0.f, 0.f};

  // bpermute byte-indices for P^T frag assembly
  int a0 = (l15 + (((2 * g) & 3) << 4)) << 2;
  int a1 = a0 + 64;

  for (int st = 0; st < 8; st++) {
    int tbase = st * 32;
    // ---- K A-frags direct from global: kf[Mtile][dslice]
    s16x8 kf[2][2];
#pragma unroll
    for (int mt = 0; mt < 2; mt++) {
      size_t krow = (size_t)(rowK + tbase + mt * 16 + l15) * 1024 + hoff;
#pragma unroll
      for (int ds = 0; ds < 2; ds++)
        kf[mt][ds] = *(const s16x8*)(kvS + krow + ds * 32 + g * 8);
    }
    // ---- V loads + transpose-scatter into per-wave swizzled LDS
    s16x8 vv[4];
#pragma unroll
    for (int i = 0; i < 4; i++)
      vv[i] = *(const s16x8*)(kvS +
                              (size_t)(rowK + tbase + i * 8 + (lane >> 3)) * 1024 +
                              512 + hoff + (lane & 7) * 8);
#pragma unroll
    for (int i = 0; i < 4; i++) {
      int kk = i * 8 + (lane >> 3);
      int dbase = (lane & 7) * 8;
#pragma unroll
      for (int j = 0; j < 8; j++) {
        int d = dbase + j;
        Vts[w][d * 32 + (kk & 7) + ((i ^ ((d >> 3) & 3)) << 3)] = vv[i][j];
      }
    }
    // ---- V^T A-frags (LDS ops in-order within wave; no barrier needed)
    s16x8 vfr[4];
#pragma unroll
    for (int dt = 0; dt < 4; dt++) {
      int d = dt * 16 + l15;
      vfr[dt] = *(const s16x8*)&Vts[w][d * 32 + ((g ^ ((d >> 3) & 3)) << 3)];
    }
    // ---- S^T = K @ Q^T  (hi+lo accumulate into same f32 acc)
    f32x4 sa[2][2];
#pragma unroll
    for (int mt = 0; mt < 2; mt++)
#pragma unroll
      for (int qt = 0; qt < 2; qt++) {
        f32x4 acc = (f32x4){0.f, 0.f, 0.f, 0.f};
        acc = __builtin_amdgcn_mfma_f32_16x16x32_bf16(kf[mt][0], qf[qt][0][0], acc, 0, 0, 0);
        acc = __builtin_amdgcn_mfma_f32_16x16x32_bf16(kf[mt][0], qf[qt][0][1], acc, 0, 0, 0);
        acc = __builtin_amdgcn_mfma_f32_16x16x32_bf16(kf[mt][1], qf[qt][1][0], acc, 0, 0, 0);
        acc = __builtin_amdgcn_mfma_f32_16x16x32_bf16(kf[mt][1], qf[qt][1][1], acc, 0, 0, 0);
        sa[mt][qt] = acc;
      }
    // ---- online softmax + P^T frags + PV, per q-tile
#pragma unroll
    for (int qt = 0; qt < 2; qt++) {
      f32x4 s0 = sa[0][qt], s1 = sa[1][qt];
      float tm = fmaxf(fmaxf(fmaxf(s0[0], s0[1]), fmaxf(s0[2], s0[3])),
                       fmaxf(fmaxf(s1[0], s1[1]), fmaxf(s1[2], s1[3])));
      tm = fmaxf(tm, __shfl_xor(tm, 16, 64));
      tm = fmaxf(tm, __shfl_xor(tm, 32, 64));
      float mn = fmaxf(mq[qt], tm);
      float p0[4], p1[4];
      float ps = 0.f;
#pragma unroll
      for (int j = 0; j < 4; j++) {
        p0[j] = __expf(s0[j] - mn);
        p1[j] = __expf(s1[j] - mn);
        ps += p0[j] + p1[j];
      }
      ps += __shfl_xor(ps, 16, 64);
      ps += __shfl_xor(ps, 32, 64);
      float sc = __expf(mq[qt] - mn);
      lq[qt] = lq[qt] * sc + ps;
      mq[qt] = mn;
#pragma unroll
      for (int dt = 0; dt < 4; dt++) ctx[dt][qt] *= sc;
      // pack hi/lo bf16 dwords: dh[0]=(t=4g,4g+1) dh[1]=(4g+2,4g+3)
      //                         dh[2]=(16+4g,16+4g+1) dh[3]=(16+4g+2,16+4g+3)
      unsigned hh[8], ll[8];
#pragma unroll
      for (int j = 0; j < 4; j++) {
        hilo(p0[j], hh[j], ll[j]);
        hilo(p1[j], hh[4 + j], ll[4 + j]);
      }
      unsigned dh0 = hh[0] | (hh[1] << 16), dh1 = hh[2] | (hh[3] << 16);
      unsigned dh2 = hh[4] | (hh[5] << 16), dh3 = hh[6] | (hh[7] << 16);
      unsigned dl0 = ll[0] | (ll[1] << 16), dl1 = ll[2] | (ll[3] << 16);
      unsigned dl2 = ll[4] | (ll[5] << 16), dl3 = ll[6] | (ll[7] << 16);
      // assemble P^T B-frag (col q=l15, k = t = g*8+i) via bpermute
      int x0 = __builtin_amdgcn_ds_bpermute(a0, (int)dh0);
      int x1 = __builtin_amdgcn_ds_bpermute(a0, (int)dh1);
      int x2 = __builtin_amdgcn_ds_bpermute(a0, (int)dh2);
      int x3 = __builtin_amdgcn_ds_bpermute(a0, (int)dh3);
      int y0 = __builtin_amdgcn_ds_bpermute(a1, (int)dh0);
      int y1 = __builtin_amdgcn_ds_bpermute(a1, (int)dh1);
      int y2 = __builtin_amdgcn_ds_bpermute(a1, (int)dh2);
      int y3 = __builtin_amdgcn_ds_bpermute(a1, (int)dh3);
      i32x4 fh;
      if (g < 2)
        fh = (i32x4){x0, x1, y0, y1};
      else
        fh = (i32x4){x2, x3, y2, y3};
      x0 = __builtin_amdgcn_ds_bpermute(a0, (int)dl0);
      x1 = __builtin_amdgcn_ds_bpermute(a0, (int)dl1);
      x2 = __builtin_amdgcn_ds_bpermute(a0, (int)dl2);
      x3 = __builtin_amdgcn_ds_bpermute(a0, (int)dl3);
      y0 = __builtin_amdgcn_ds_bpermute(a1, (int)dl0);
      y1 = __builtin_amdgcn_ds_bpermute(a1, (int)dl1);
      y2 = __builtin_amdgcn_ds_bpermute(a1, (int)dl2);
      y3 = __builtin_amdgcn_ds_bpermute(a1, (int)dl3);
      i32x4 fl;
      if (g < 2)
        fl = (i32x4){x0, x1, y0, y1};
      else
        fl = (i32x4){x2, x3, y2, y3};
      s16x8 pfh = __builtin_bit_cast(s16x8, fh);
      s16x8 pfl = __builtin_bit_cast(s16x8, fl);
      // ctx^T += V^T @ P^T
#pragma unroll
      for (int dt = 0; dt < 4; dt++) {
        ctx[dt][qt] =
            __builtin_amdgcn_mfma_f32_16x16x32_bf16(vfr[dt], pfh, ctx[dt][qt], 0, 0, 0);
        ctx[dt][qt] =
            __builtin_amdgcn_mfma_f32_16x16x32_bf16(vfr[dt], pfl, ctx[dt][qt], 0, 0, 0);
      }
    }
  }

  // ---- stash per-wave state for in-block combine
  if (g == 0) {
#pragma unroll
    for (int qt = 0; qt < 2; qt++) {
      cm[w][qt * 16 + l15] = mq[qt];
      cl[w][qt * 16 + l15] = lq[qt];
    }
  }
#pragma unroll
  for (int dt = 0; dt < 4; dt++)
#pragma unroll
    for (int qt = 0; qt < 2; qt++) {
      f32x4 v = ctx[dt][qt];
      int q = qt * 16 + l15;
      int dd = dt * 16 + g * 4;
#pragma unroll
      for (int r = 0; r < 4; r++) ctxc[w][q][dd + r] = v[r];
    }
  __syncthreads();

  // ---- combine 4 wave partials -> one chunk partial
  {
    int q = tid >> 3, dg = tid & 7;
    float m0 = cm[0][q], m1 = cm[1][q], m2 = cm[2][q], m3 = cm[3][q];
    float ms = fmaxf(fmaxf(m0, m1), fmaxf(m2, m3));
    float e0 = __expf(m0 - ms), e1 = __expf(m1 - ms);
    float e2 = __expf(m2 - ms), e3 = __expf(m3 - ms);
    float ls = e0 * cl[0][q] + e1 * cl[1][q] + e2 * cl[2][q] + e3 * cl[3][q];
    int pbase = (((k * 8 + b) * 8 + h) * 8 + c) * 32;
    size_t urow = (size_t)(pbase + q) * 64 + dg * 8;
#pragma unroll
    for (int half = 0; half < 2; half++) {
      int d0 = dg * 8 + half * 4;
      f4 acc = e0 * *(const f4*)&ctxc[0][q][d0] + e1 * *(const f4*)&ctxc[1][q][d0] +
               e2 * *(const f4*)&ctxc[2][q][d0] + e3 * *(const f4*)&ctxc[3][q][d0];
      *(f4*)&pu[urow + half * 4] = acc;
    }
    if (dg == 0) {
      pm[pbase + q] = ms;
      pl[pbase + q] = ls;
    }
  }
}

// ---------------- 8. combine + output chain -------------------------------
__global__ __launch_bounds__(256) void out_chain(
    const float* __restrict__ pm, const float* __restrict__ pl,
    const float* __restrict__ pu, const float* __restrict__ Watt,
    const float* __restrict__ batt, const float* __restrict__ Wo,
    const float* __restrict__ bo, const float* __restrict__ gk,
    float* __restrict__ out) {
  __shared__ float Cs[8][512];
  __shared__ float T1[8][512];
  int tid = threadIdx.x;
  int r0 = blockIdx.x * 8;
  { // combine chunk partials -> ctx
    int ri = tid >> 5, hh = (tid >> 2) & 7, dq = tid & 3;
    int d0 = dq * 16;
    int r = r0 + ri;
    int k = r >> 8, b = (r >> 5) & 7, s = r & 31;
    int pb0 = ((((k * 8 + b) * 8 + hh) * 8) * 32) + s; // c=0
    float mstar = -3.0e38f;
#pragma unroll
    for (int cc = 0; cc < 8; cc++) mstar = fmaxf(mstar, pm[pb0 + cc * 32]);
    float ls = 0.f;
    f4 us[4];
#pragma unroll
    for (int t4 = 0; t4 < 4; t4++) us[t4] = (f4){0.f, 0.f, 0.f, 0.f};
#pragma unroll
    for (int cc = 0; cc < 8; cc++) {
      int pidx = pb0 + cc * 32;
      float wv = __expf(pm[pidx] - mstar);
      ls += wv * pl[pidx];
      const f4* up = (const f4*)&pu[(size_t)pidx * 64 + d0];
#pragma unroll
      for (int t4 = 0; t4 < 4; t4++) us[t4] += up[t4] * wv;
    }
    float inv = 1.f / ls;
#pragma unroll
    for (int t4 = 0; t4 < 4; t4++)
#pragma unroll
      for (int j = 0; j < 4; j++) Cs[ri][hh * 64 + d0 + t4 * 4 + j] = us[t4][j] * inv;
  }
  __syncthreads();
  int c0 = tid, c1 = tid + 256;
  { // T1 = Cs @ W_attn_out + b_attn_out
    float a0[8], a1[8];
#pragma unroll
    for (int i = 0; i < 8; i++) { a0[i] = 0.f; a1[i] = 0.f; }
#pragma unroll 4
    for (int l = 0; l < 512; l++) {
      float w0 = Watt[(size_t)l * 512 + c0];
      float w1 = Watt[(size_t)l * 512 + c1];
#pragma unroll
      for (int i = 0; i < 8; i++) {
        float z = Cs[i][l];
        a0[i] += z * w0;
        a1[i] += z * w1;
      }
    }
    float bb0 = batt[c0], bb1 = batt[c1];
#pragma unroll
    for (int i = 0; i < 8; i++) {
      T1[i][c0] = a0[i] + bb0;
      T1[i][c1] = a1[i] + bb1;
    }
  }
  __syncthreads();
  { // out = (T1 @ W_o + b_o) * gk, permuted to (b, k*32+s, d)
    float a0[8], a1[8];
#pragma unroll
    for (int i = 0; i < 8; i++) { a0[i] = 0.f; a1[i] = 0.f; }
#pragma unroll 4
    for (int l = 0; l < 512; l++) {
      float w0 = Wo[(size_t)l * 512 + c0];
      float w1 = Wo[(size_t)l * 512 + c1];
#pragma unroll
      for (int i = 0; i < 8; i++) {
        float z = T1[i][l];
        a0[i] += z * w0;
        a1[i] += z * w1;
      }
    }
    float bb0 = bo[c0], bb1 = bo[c1];
#pragma unroll
    for (int i = 0; i < 8; i++) {
      int r = r0 + i;
      int k = r >> 8, b = (r >> 5) & 7, s = r & 31;
      float g = gk[r];
      size_t orow = (size_t)(b * 96 + k * 32 + s) * 512;
      out[orow + c0] = (a0[i] + bb0) * g;
      out[orow + c1] = (a1[i] + bb1) * g;
    }
  }
}

// ---------------------------------------------------------------------------
extern "C" void kernel_launch(void* const* d_in, const int* in_sizes, int n_in,
                              void* d_out, int out_size, void* d_ws, size_t ws_size,
                              hipStream_t stream) {
  const float* proj = (const float*)d_in[0];
  const float* hctc = (const float*)d_in[1];
  const float* A = (const float*)d_in[2];
  const int* spikes = (const int*)d_in[3];
  const float* Wmem = (const float*)d_in[4];
  const float* bmem = (const float*)d_in[5];
  const float* Wkv = (const float*)d_in[6];
  const float* bkv = (const float*)d_in[7];
  const float* Wq = (const float*)d_in[8];
  const float* bq = (const float*)d_in[9];
  const float* Wqkv = (const float*)d_in[10];
  const float* bqkv = (const float*)d_in[11];
  const float* Watt = (const float*)d_in[12];
  const float* batt = (const float*)d_in[13];
  const float* Wo = (const float*)d_in[14];
  const float* bo = (const float*)d_in[15];
  float* out = (float*)d_out;
  (void)in_sizes; (void)n_in; (void)out_size; (void)ws_size;

  char* w = (char*)d_ws;
  bf16* projb = (bf16*)(w + 0);            //  67108864 B
  bf16* kvb   = (bf16*)(w + 67108864);     // 134217728 B
  bf16* w2t   = (bf16*)(w + 201326592);    //   1048576 B
  float* b2   = (float*)(w + 202375168);   //      4096 B
  int* spk    = (int*)(w + 202379264);     //      3072 B
  float* warr = (float*)(w + 202382336);   //     52224 B
  float* winv = (float*)(w + 202434560);   //      3072 B
  float* gk   = (float*)(w + 202437632);   //      3072 B
  float* Zb   = (float*)(w + 202440704);   //   1572864 B
  float* qws  = (float*)(w + 204013568);   //   1572864 B
  float* pm   = (float*)(w + 205586432);   //    196608 B
  float* pl   = (float*)(w + 205783040);   //    196608 B
  float* pu   = (float*)(w + 205979648);   //  12582912 B -> end 218562560

  prep_w2t<<<dim3(16, 8), 256, 0, stream>>>(Wmem, Wqkv, w2t);
  bias2_kernel<<<4, 256, 0, stream>>>(bmem, Wqkv, bqkv, b2);
  cvt_bf16<<<16384, 256, 0, stream>>>(proj, projb);
  kv_gemm<<<dim3(8, 512), 256, 0, stream>>>(projb, w2t, b2, kvb);
  topk_kernel<<<24, 128, 0, stream>>>(A, spikes, spk, warr, winv, gk);
  z_gather<<<768, 256, 0, stream>>>(hctc, spk, warr, winv, Zb);
  seed_chain<<<96, 256, 0, stream>>>(Zb, Wkv, bkv, Wq, bq, Wqkv, bqkv, qws);
  attn_kernel<<<1536, 256, 0, stream>>>(kvb, qws, pm, pl, pu);
  out_chain<<<96, 256, 0, stream>>>(pm, pl, pu, Watt, batt, Wo, bo, gk, out);
}

// Round 2
// 1125.149 us; speedup vs baseline: 1.2179x; 1.0236x over previous
//
#include <hip/hip_runtime.h>
#include <hip/hip_bf16.h>

// ---------------------------------------------------------------------------
// CTCBridgeSparseSlot on MI355X.
// Pipeline:
//   1. prep_w2t   : W2^T = (W_mem @ W_qkv[:,512:1536])^T  -> bf16 [1024][512]
//      bias2      : b2 = b_mem @ Wsub + b_qkv[512:1536]
//   2. cvt_bf16   : proj_feats f32 -> bf16
//   3. kv_gemm    : kv[65536][1024] = proj_bf16 @ W2 + b2  (bf16 MFMA,
//                   global_load_lds staging, LDS-staged coalesced epilogue)
//   4. topk_kernel: per (k,b): window-mean scores, exact top-32
//   5. z_gather   : Z[768][512] weighted h_ctc window means (f32)
//   6. seed_chain : q = (tanh((Z@Wkv_k + b) @ W_q + b_q)) @ Wqh + bqh (f32)
//   7. attn_kernel: MFMA flash attention, 3 spike-tracks merged per block
//                   (kv read once), blocks = (b,h,chunk), 4 waves x 256 keys
//   8. out_chain  : combine partials -> ctx -> @W_attn_out -> @W_o -> *gk -> out
// ---------------------------------------------------------------------------

#define T_LEN 8192
#define DMODEL 512
#define NROWS 768 // 3*8*32

typedef __hip_bfloat16 bf16;
typedef short s16x8 __attribute__((ext_vector_type(8)));
typedef short s16x4 __attribute__((ext_vector_type(4)));
typedef float f32x4 __attribute__((ext_vector_type(4)));
typedef float f4 __attribute__((ext_vector_type(4)));
typedef float f2 __attribute__((ext_vector_type(2)));
typedef int i32x4 __attribute__((ext_vector_type(4)));

typedef __attribute__((address_space(3))) void* lds_vp;
typedef const __attribute__((address_space(1))) void* gbl_cvp;

// ---------------- 1. combined weight prep ---------------------------------
__global__ __launch_bounds__(256) void prep_w2t(const float* __restrict__ Wmem,
                                                const float* __restrict__ Wqkv,
                                                bf16* __restrict__ w2t) {
  __shared__ __align__(16) float As[16][68]; // As[l][j] = Wqkv[l0+l][512+j0+j]
  __shared__ __align__(16) float Bs[16][68]; // Bs[l][i] = Wmem[i0+i][l0+l]
  int tid = threadIdx.x;
  int j0 = blockIdx.x * 64, i0 = blockIdx.y * 64;
  int ty = tid >> 4, tx = tid & 15;
  float c[4][4];
#pragma unroll
  for (int a = 0; a < 4; a++)
#pragma unroll
    for (int b = 0; b < 4; b++) c[a][b] = 0.f;

  for (int l0 = 0; l0 < 512; l0 += 16) {
    __syncthreads();
    {
      int l = tid >> 4, j4 = (tid & 15) * 4;
      f4 v = *(const f4*)&Wqkv[(size_t)(l0 + l) * 1536 + 512 + j0 + j4];
      *(f4*)&As[l][j4] = v;
    }
    {
      int i = tid >> 2, l4 = (tid & 3) * 4;
      f4 v = *(const f4*)&Wmem[(size_t)(i0 + i) * 512 + l0 + l4];
      Bs[l4 + 0][i] = v[0];
      Bs[l4 + 1][i] = v[1];
      Bs[l4 + 2][i] = v[2];
      Bs[l4 + 3][i] = v[3];
    }
    __syncthreads();
#pragma unroll
    for (int l = 0; l < 16; l++) {
      f4 a = *(f4*)&As[l][ty * 4];
      f4 b = *(f4*)&Bs[l][tx * 4];
#pragma unroll
      for (int jj = 0; jj < 4; jj++)
#pragma unroll
        for (int ii = 0; ii < 4; ii++) c[jj][ii] += a[jj] * b[ii];
    }
  }
#pragma unroll
  for (int jj = 0; jj < 4; jj++)
#pragma unroll
    for (int ii = 0; ii < 4; ii++)
      w2t[(size_t)(j0 + ty * 4 + jj) * 512 + i0 + tx * 4 + ii] =
          __float2bfloat16(c[jj][ii]);
}

__global__ __launch_bounds__(256) void bias2_kernel(const float* __restrict__ bmem,
                                                    const float* __restrict__ Wqkv,
                                                    const float* __restrict__ bqkv,
                                                    float* __restrict__ b2) {
  // 16 blocks x 256 threads; block covers 64 cols, 4-way split over l
  __shared__ float red[4][64];
  int j0 = blockIdx.x * 64;
  int jc = threadIdx.x & 63, lp = threadIdx.x >> 6;
  int j = j0 + jc;
  float acc = 0.f;
  for (int l = lp * 128; l < lp * 128 + 128; l++)
    acc += bmem[l] * Wqkv[(size_t)l * 1536 + 512 + j];
  red[lp][jc] = acc;
  __syncthreads();
  if (threadIdx.x < 64) {
    float s = red[0][jc] + red[1][jc] + red[2][jc] + red[3][jc];
    b2[j0 + jc] = s + bqkv[512 + j0 + jc];
  }
}

// ---------------- 2. proj -> bf16 -----------------------------------------
__global__ __launch_bounds__(256) void cvt_bf16(const float* __restrict__ x,
                                                bf16* __restrict__ y) {
  int i = blockIdx.x * 256 + threadIdx.x; // 8 elems each, n=33554432
  const f4* p = (const f4*)x;
  f4 a = p[(size_t)i * 2], b = p[(size_t)i * 2 + 1];
  __align__(16) bf16 o[8];
  o[0] = __float2bfloat16(a[0]);
  o[1] = __float2bfloat16(a[1]);
  o[2] = __float2bfloat16(a[2]);
  o[3] = __float2bfloat16(a[3]);
  o[4] = __float2bfloat16(b[0]);
  o[5] = __float2bfloat16(b[1]);
  o[6] = __float2bfloat16(b[2]);
  o[7] = __float2bfloat16(b[3]);
  ((f4*)y)[i] = *(f4*)o;
}

// ---------------- 3. big GEMM: kv = proj_bf16 @ W2 + b2 (bf16 MFMA) -------
// A: [65536][512] bf16. Bt: [1024][512] bf16. C: [65536][1024] bf16.
// Tile 128x128, BK=32, 4 waves. global_load_lds(16B) staging, swapped-operand
// MFMA (lane holds 4 consecutive C cols), LDS-staged coalesced 16B stores.
__global__ __launch_bounds__(256) void kv_gemm(const bf16* __restrict__ A,
                                               const bf16* __restrict__ Bt,
                                               const float* __restrict__ bias,
                                               bf16* __restrict__ C) {
  __shared__ __align__(16) char sm[16384];
  bf16* As = (bf16*)sm;           // [128][32]
  bf16* Bs = (bf16*)(sm + 8192);  // [128][32]
  int tid = threadIdx.x;
  int lane = tid & 63, wave = tid >> 6;
  int wm = wave & 1, wn = wave >> 1;
  int m0 = blockIdx.y * 128, n0 = blockIdx.x * 128;
  int l15 = lane & 15, g = lane >> 4;
  f32x4 acc[4][4];
#pragma unroll
  for (int mi = 0; mi < 4; mi++)
#pragma unroll
    for (int ni = 0; ni < 4; ni++) acc[mi][ni] = (f32x4){0.f, 0.f, 0.f, 0.f};

  int arow = tid >> 2, akq = (tid & 3) * 8;
  for (int k0 = 0; k0 < 512; k0 += 32) {
    __syncthreads();
#pragma unroll
    for (int i = 0; i < 2; i++) {
      const bf16* ga = &A[(size_t)(m0 + i * 64 + arow) * 512 + k0 + akq];
      const bf16* gb = &Bt[(size_t)(n0 + i * 64 + arow) * 512 + k0 + akq];
      __builtin_amdgcn_global_load_lds((gbl_cvp)ga,
                                       (lds_vp)(sm + (i * 256 + wave * 64) * 16),
                                       16, 0, 0);
      __builtin_amdgcn_global_load_lds((gbl_cvp)gb,
                                       (lds_vp)(sm + 8192 + (i * 256 + wave * 64) * 16),
                                       16, 0, 0);
    }
    __syncthreads();
    s16x8 af[4], bfr[4];
#pragma unroll
    for (int mi = 0; mi < 4; mi++)
      af[mi] = *(s16x8*)&As[(wm * 64 + mi * 16 + l15) * 32 + g * 8];
#pragma unroll
    for (int ni = 0; ni < 4; ni++)
      bfr[ni] = *(s16x8*)&Bs[(wn * 64 + ni * 16 + l15) * 32 + g * 8];
    // swapped operands: D row-dim = Bt rows (C cols), D col-dim = A rows.
    // lane holds C row (l15), C cols g*4+reg -> 4 consecutive cols per lane.
#pragma unroll
    for (int mi = 0; mi < 4; mi++)
#pragma unroll
      for (int ni = 0; ni < 4; ni++)
        acc[mi][ni] = __builtin_amdgcn_mfma_f32_16x16x32_bf16(bfr[ni], af[mi],
                                                              acc[mi][ni], 0, 0, 0);
  }

  // epilogue: 4 passes (mi); stage [32][136] bf16 tile in LDS, 16B stores
  short* ep = (short*)sm;
  int band = wm * 16 + l15;
#pragma unroll
  for (int mi = 0; mi < 4; mi++) {
    __syncthreads();
#pragma unroll
    for (int ni = 0; ni < 4; ni++) {
      int c0 = wn * 64 + ni * 16 + g * 4;
      f4 bv = *(const f4*)&bias[n0 + c0];
      f32x4 v = acc[mi][ni];
      __align__(8) bf16 pk[4];
#pragma unroll
      for (int r = 0; r < 4; r++) pk[r] = __float2bfloat16(v[r] + bv[r]);
      *(s16x4*)&ep[band * 136 + c0] = *(s16x4*)pk;
    }
    __syncthreads();
#pragma unroll
    for (int it = 0; it < 2; it++) {
      int cidx = it * 256 + tid;
      int brow = cidx >> 4, ch = cidx & 15;
      s16x8 val = *(s16x8*)&ep[brow * 136 + ch * 8];
      int row = m0 + (brow >> 4) * 64 + mi * 16 + (brow & 15);
      *(s16x8*)&C[(size_t)row * 1024 + n0 + ch * 8] = val;
    }
  }
}

// ---------------- 4. top-k spike selection --------------------------------
__global__ __launch_bounds__(128) void topk_kernel(const float* __restrict__ A,
                                                   const int* __restrict__ spikes,
                                                   int* __restrict__ spk_out,
                                                   float* __restrict__ w_out,
                                                   float* __restrict__ winv_out,
                                                   float* __restrict__ gk_out) {
  int kb = blockIdx.x; // (k*8+b) in [0,24)
  int i = threadIdx.x; // [0,128)
  const float* Ab = A + (size_t)kb * T_LEN;
  __shared__ float s_sc[128];
  __shared__ int s_sp[128];
  __shared__ int s_sel[32];
  int t0 = spikes[kb * 128 + i];
  s_sp[i] = t0;
  float sum = 0.f;
  int cnt = 0;
#pragma unroll
  for (int o = -8; o <= 8; o++) {
    int t = t0 + o;
    if (t >= 0 && t < T_LEN) { sum += Ab[t]; cnt++; }
  }
  float sc = (t0 >= 0 && t0 < T_LEN) ? (sum / (float)max(cnt, 1)) : -1e9f;
  s_sc[i] = sc;
  __syncthreads();
  float sci = s_sc[i];
  int rank = 0;
  for (int j = 0; j < 128; j++) {
    float scj = s_sc[j];
    if (scj > sci || (scj == sci && j < i)) rank++;
  }
  if (rank < 32) s_sel[rank] = i;
  __syncthreads();
  if (i < 32) {
    int sel = s_sel[i];
    int spkv = s_sp[sel];
    float conf = s_sc[sel];
    int r = kb * 32 + i;
    spk_out[r] = spkv;
    bool vmask = (spkv >= 0 && spkv < T_LEN);
    float wsum = 0.f;
#pragma unroll
    for (int o = 0; o < 17; o++) {
      int t = spkv + o - 8;
      bool v = vmask && (t >= 0) && (t < T_LEN);
      int tc = min(max(t, 0), T_LEN - 1);
      float off = (float)(o - 8) * 0.25f;
      float g = expf(-0.5f * off * off);
      float wv = v ? g * Ab[tc] : 0.f;
      wsum += wv;
      w_out[r * 17 + o] = wv;
    }
    winv_out[r] = 1.f / (wsum + 1e-6f);
    gk_out[r] = vmask ? (1.f / (1.f + expf(-2.f * conf))) : 0.f;
  }
}

// ---------------- 5. Z gather ---------------------------------------------
__global__ __launch_bounds__(256) void z_gather(const float* __restrict__ hctc,
                                                const int* __restrict__ spk,
                                                const float* __restrict__ warr,
                                                const float* __restrict__ winv,
                                                float* __restrict__ Z) {
  int r = blockIdx.x; // [0,768)
  int tid = threadIdx.x;
  int kb = r >> 5;
  const float* h = hctc + (size_t)kb * T_LEN * DMODEL;
  int sp = spk[r];
  float wi = winv[r];
  float acc0 = 0.f, acc1 = 0.f;
#pragma unroll
  for (int o = 0; o < 17; o++) {
    float wv = warr[r * 17 + o];
    int t = min(max(sp + o - 8, 0), T_LEN - 1);
    const float* hp = h + (size_t)t * DMODEL;
    acc0 += wv * hp[tid];
    acc1 += wv * hp[tid + 256];
  }
  Z[(size_t)r * DMODEL + tid] = acc0 * wi;
  Z[(size_t)r * DMODEL + tid + 256] = acc1 * wi;
}

// ---------------- 6. seed chain: Z -> Kseed -> tanh -> q ------------------
__global__ __launch_bounds__(256) void seed_chain(
    const float* __restrict__ Z, const float* __restrict__ Wkv,
    const float* __restrict__ bkv, const float* __restrict__ Wq,
    const float* __restrict__ bq, const float* __restrict__ Wqkv,
    const float* __restrict__ bqkv, float* __restrict__ qout) {
  __shared__ float Zs[8][512];
  __shared__ float T1[8][512];
  __shared__ float T2[8][512];
  int tid = threadIdx.x;
  int r0 = blockIdx.x * 8;
  int k = r0 >> 8;
  for (int ii = 0; ii < 16; ii++) {
    int idx = tid + ii * 256;
    ((float*)Zs)[idx] = Z[(size_t)r0 * 512 + idx];
  }
  __syncthreads();
  int c0 = tid, c1 = tid + 256;
  { // Kseed = Zs @ Wkv[k][:, :512] + bkv[k][:512]
    const float* W = Wkv + (size_t)k * 512 * 1024;
    float a0[8], a1[8];
#pragma unroll
    for (int i = 0; i < 8; i++) { a0[i] = 0.f; a1[i] = 0.f; }
#pragma unroll 4
    for (int l = 0; l < 512; l++) {
      float w0 = W[(size_t)l * 1024 + c0];
      float w1 = W[(size_t)l * 1024 + c1];
#pragma unroll
      for (int i = 0; i < 8; i++) {
        float z = Zs[i][l];
        a0[i] += z * w0;
        a1[i] += z * w1;
      }
    }
    float bb0 = bkv[k * 1024 + c0], bb1 = bkv[k * 1024 + c1];
#pragma unroll
    for (int i = 0; i < 8; i++) {
      T1[i][c0] = a0[i] + bb0;
      T1[i][c1] = a1[i] + bb1;
    }
  }
  __syncthreads();
  { // T2 = tanh(T1 @ Wq + bq)
    float a0[8], a1[8];
#pragma unroll
    for (int i = 0; i < 8; i++) { a0[i] = 0.f; a1[i] = 0.f; }
#pragma unroll 4
    for (int l = 0; l < 512; l++) {
      float w0 = Wq[(size_t)l * 512 + c0];
      float w1 = Wq[(size_t)l * 512 + c1];
#pragma unroll
      for (int i = 0; i < 8; i++) {
        float z = T1[i][l];
        a0[i] += z * w0;
        a1[i] += z * w1;
      }
    }
    float bb0 = bq[c0], bb1 = bq[c1];
#pragma unroll
    for (int i = 0; i < 8; i++) {
      T2[i][c0] = tanhf(a0[i] + bb0);
      T2[i][c1] = tanhf(a1[i] + bb1);
    }
  }
  __syncthreads();
  { // q = T2 @ Wqkv[:, :512] + bqkv[:512]
    float a0[8], a1[8];
#pragma unroll
    for (int i = 0; i < 8; i++) { a0[i] = 0.f; a1[i] = 0.f; }
#pragma unroll 4
    for (int l = 0; l < 512; l++) {
      float w0 = Wqkv[(size_t)l * 1536 + c0];
      float w1 = Wqkv[(size_t)l * 1536 + c1];
#pragma unroll
      for (int i = 0; i < 8; i++) {
        float z = T2[i][l];
        a0[i] += z * w0;
        a1[i] += z * w1;
      }
    }
    float bb0 = bqkv[c0], bb1 = bqkv[c1];
#pragma unroll
    for (int i = 0; i < 8; i++) {
      qout[(size_t)(r0 + i) * 512 + c0] = a0[i] + bb0;
      qout[(size_t)(r0 + i) * 512 + c1] = a1[i] + bb1;
    }
  }
}

// ---------------- 7. attention (MFMA flash, 3 tracks merged) --------------
// block = (b,h,c): 3x32 queries x 1024 keys, 4 waves x 256 keys each.
// K/V read ONCE per block, used by all 3 spike-tracks (was 3x traffic).
// Q hi/lo frags staged in LDS; per-track softmax state in registers.

static __device__ __forceinline__ unsigned bf16rne(float f) {
  unsigned x = __builtin_bit_cast(unsigned, f);
  return (x + 0x7fffu + ((x >> 16) & 1u)) >> 16;
}
static __device__ __forceinline__ float bfval(unsigned u) {
  return __builtin_bit_cast(float, u << 16);
}
static __device__ __forceinline__ void hilo(float x, unsigned& h, unsigned& l) {
  h = bf16rne(x);
  l = bf16rne(x - bfval(h));
}

__global__ __launch_bounds__(256) void attn_kernel(const bf16* __restrict__ kv,
                                                   const float* __restrict__ qws,
                                                   float* __restrict__ pm,
                                                   float* __restrict__ pl,
                                                   float* __restrict__ pu) {
  __shared__ __align__(16) char smem[40960];
  short* Vts = (short*)smem;            // loop: [4][2048] per-wave V^T swizzled
  short* Qls = (short*)(smem + 16384);  // loop: [12 slots][2 hl][64 lane][8]
  float* ctxc = (float*)smem;           // combine: [4][32][68]
  float* cmS = (float*)(smem + 34816);  // combine: [4][32]
  float* clS = (float*)(smem + 35328);  // combine: [4][32]

  int tid = threadIdx.x;
  int w = tid >> 6, lane = tid & 63;
  int l15 = lane & 15, g = lane >> 4;
  int bx = blockIdx.x;
  int c = bx & 7, h = (bx >> 3) & 7, b = bx >> 6; // 512 blocks
  const short* kvS = (const short*)kv;
  int hoff = h * 64;
  int rowK = b * T_LEN + c * 1024 + w * 256;

  // ---- Q staging into LDS: slot = kk*4 + qt*2 + ds, hi/lo bf16 frags
#pragma unroll
  for (int p = 0; p < 3; p++) {
    int slot = p * 4 + (tid >> 6);
    int kk = slot >> 2, qt = (slot >> 1) & 1, ds = slot & 1;
    int ln = tid & 63;
    int sl15 = ln & 15, sg = ln >> 4;
    const float* qp = qws + (size_t)((kk * 8 + b) * 32 + qt * 16 + sl15) * 512 +
                      hoff + ds * 32 + sg * 8;
    f4 x = *(const f4*)qp;
    f4 y = *(const f4*)(qp + 4);
    x *= 0.125f;
    y *= 0.125f;
    s16x8 hi, lo;
#pragma unroll
    for (int j = 0; j < 4; j++) {
      unsigned hb, lb;
      hilo(x[j], hb, lb);
      hi[j] = (short)hb;
      lo[j] = (short)lb;
      hilo(y[j], hb, lb);
      hi[4 + j] = (short)hb;
      lo[4 + j] = (short)lb;
    }
    *(s16x8*)&Qls[((slot * 2 + 0) * 64 + ln) * 8] = hi;
    *(s16x8*)&Qls[((slot * 2 + 1) * 64 + ln) * 8] = lo;
  }
  __syncthreads();

  float mq[3][2];
  float lsm[3][2];
  f32x4 ctx[3][4][2]; // [track][dtile][qtile]
#pragma unroll
  for (int kk = 0; kk < 3; kk++)
#pragma unroll
    for (int qt = 0; qt < 2; qt++) {
      mq[kk][qt] = -3.0e38f;
      lsm[kk][qt] = 0.f;
    }
#pragma unroll
  for (int kk = 0; kk < 3; kk++)
#pragma unroll
    for (int dt = 0; dt < 4; dt++)
#pragma unroll
      for (int qt = 0; qt < 2; qt++) ctx[kk][dt][qt] = (f32x4){0.f, 0.f, 0.f, 0.f};

  // bpermute byte-indices for P^T frag assembly
  int a0 = (l15 + (((2 * g) & 3) << 4)) << 2;
  int a1 = a0 + 64;

  for (int st = 0; st < 8; st++) {
    int tbase = st * 32;
    // ---- K A-frags direct from global: kf[Mtile][dslice]
    s16x8 kf[2][2];
#pragma unroll
    for (int mt = 0; mt < 2; mt++) {
      size_t krow = (size_t)(rowK + tbase + mt * 16 + l15) * 1024 + hoff;
#pragma unroll
      for (int ds = 0; ds < 2; ds++)
        kf[mt][ds] = *(const s16x8*)(kvS + krow + ds * 32 + g * 8);
    }
    // ---- V loads + transpose-scatter into per-wave swizzled LDS
    {
      s16x8 vv[4];
#pragma unroll
      for (int i = 0; i < 4; i++)
        vv[i] = *(const s16x8*)(kvS +
                                (size_t)(rowK + tbase + i * 8 + (lane >> 3)) * 1024 +
                                512 + hoff + (lane & 7) * 8);
#pragma unroll
      for (int i = 0; i < 4; i++) {
        int tk = i * 8 + (lane >> 3);
        int dbase = (lane & 7) * 8;
#pragma unroll
        for (int j = 0; j < 8; j++) {
          int d = dbase + j;
          Vts[w * 2048 + d * 32 + (tk & 7) + ((i ^ ((d >> 3) & 3)) << 3)] = vv[i][j];
        }
      }
    }
    // ---- V^T A-frags (LDS ops in-order within wave; no barrier needed)
    s16x8 vfr[4];
#pragma unroll
    for (int dt = 0; dt < 4; dt++) {
      int d = dt * 16 + l15;
      vfr[dt] = *(const s16x8*)&Vts[w * 2048 + d * 32 + ((g ^ ((d >> 3) & 3)) << 3)];
    }
    // ---- per spike-track: S, softmax, PV
#pragma unroll
    for (int kk = 0; kk < 3; kk++) {
      s16x8 qf[2][2][2];
#pragma unroll
      for (int qt = 0; qt < 2; qt++)
#pragma unroll
        for (int ds = 0; ds < 2; ds++)
#pragma unroll
          for (int hl = 0; hl < 2; hl++)
            qf[qt][ds][hl] =
                *(const s16x8*)&Qls[(((kk * 4 + qt * 2 + ds) * 2 + hl) * 64 + lane) * 8];
      // S^T = K @ Q^T (hi+lo accumulate)
      f32x4 sa[2][2];
#pragma unroll
      for (int mt = 0; mt < 2; mt++)
#pragma unroll
        for (int qt = 0; qt < 2; qt++) {
          f32x4 acc = (f32x4){0.f, 0.f, 0.f, 0.f};
          acc = __builtin_amdgcn_mfma_f32_16x16x32_bf16(kf[mt][0], qf[qt][0][0], acc, 0, 0, 0);
          acc = __builtin_amdgcn_mfma_f32_16x16x32_bf16(kf[mt][0], qf[qt][0][1], acc, 0, 0, 0);
          acc = __builtin_amdgcn_mfma_f32_16x16x32_bf16(kf[mt][1], qf[qt][1][0], acc, 0, 0, 0);
          acc = __builtin_amdgcn_mfma_f32_16x16x32_bf16(kf[mt][1], qf[qt][1][1], acc, 0, 0, 0);
          sa[mt][qt] = acc;
        }
#pragma unroll
      for (int qt = 0; qt < 2; qt++) {
        f32x4 s0 = sa[0][qt], s1 = sa[1][qt];
        float tm = fmaxf(fmaxf(fmaxf(s0[0], s0[1]), fmaxf(s0[2], s0[3])),
                         fmaxf(fmaxf(s1[0], s1[1]), fmaxf(s1[2], s1[3])));
        tm = fmaxf(tm, __shfl_xor(tm, 16, 64));
        tm = fmaxf(tm, __shfl_xor(tm, 32, 64));
        float mn = fmaxf(mq[kk][qt], tm);
        float p0[4], p1[4];
        float ps = 0.f;
#pragma unroll
        for (int j = 0; j < 4; j++) {
          p0[j] = __expf(s0[j] - mn);
          p1[j] = __expf(s1[j] - mn);
          ps += p0[j] + p1[j];
        }
        ps += __shfl_xor(ps, 16, 64);
        ps += __shfl_xor(ps, 32, 64);
        float sc = __expf(mq[kk][qt] - mn);
        lsm[kk][qt] = lsm[kk][qt] * sc + ps;
        mq[kk][qt] = mn;
#pragma unroll
        for (int dt = 0; dt < 4; dt++) ctx[kk][dt][qt] *= sc;
        unsigned hh[8], ll[8];
#pragma unroll
        for (int j = 0; j < 4; j++) {
          hilo(p0[j], hh[j], ll[j]);
          hilo(p1[j], hh[4 + j], ll[4 + j]);
        }
        unsigned dh0 = hh[0] | (hh[1] << 16), dh1 = hh[2] | (hh[3] << 16);
        unsigned dh2 = hh[4] | (hh[5] << 16), dh3 = hh[6] | (hh[7] << 16);
        unsigned dl0 = ll[0] | (ll[1] << 16), dl1 = ll[2] | (ll[3] << 16);
        unsigned dl2 = ll[4] | (ll[5] << 16), dl3 = ll[6] | (ll[7] << 16);
        int x0 = __builtin_amdgcn_ds_bpermute(a0, (int)dh0);
        int x1 = __builtin_amdgcn_ds_bpermute(a0, (int)dh1);
        int x2 = __builtin_amdgcn_ds_bpermute(a0, (int)dh2);
        int x3 = __builtin_amdgcn_ds_bpermute(a0, (int)dh3);
        int y0 = __builtin_amdgcn_ds_bpermute(a1, (int)dh0);
        int y1 = __builtin_amdgcn_ds_bpermute(a1, (int)dh1);
        int y2 = __builtin_amdgcn_ds_bpermute(a1, (int)dh2);
        int y3 = __builtin_amdgcn_ds_bpermute(a1, (int)dh3);
        i32x4 fh;
        if (g < 2)
          fh = (i32x4){x0, x1, y0, y1};
        else
          fh = (i32x4){x2, x3, y2, y3};
        x0 = __builtin_amdgcn_ds_bpermute(a0, (int)dl0);
        x1 = __builtin_amdgcn_ds_bpermute(a0, (int)dl1);
        x2 = __builtin_amdgcn_ds_bpermute(a0, (int)dl2);
        x3 = __builtin_amdgcn_ds_bpermute(a0, (int)dl3);
        y0 = __builtin_amdgcn_ds_bpermute(a1, (int)dl0);
        y1 = __builtin_amdgcn_ds_bpermute(a1, (int)dl1);
        y2 = __builtin_amdgcn_ds_bpermute(a1, (int)dl2);
        y3 = __builtin_amdgcn_ds_bpermute(a1, (int)dl3);
        i32x4 fl;
        if (g < 2)
          fl = (i32x4){x0, x1, y0, y1};
        else
          fl = (i32x4){x2, x3, y2, y3};
        s16x8 pfh = __builtin_bit_cast(s16x8, fh);
        s16x8 pfl = __builtin_bit_cast(s16x8, fl);
#pragma unroll
        for (int dt = 0; dt < 4; dt++) {
          ctx[kk][dt][qt] =
              __builtin_amdgcn_mfma_f32_16x16x32_bf16(vfr[dt], pfh, ctx[kk][dt][qt], 0, 0, 0);
          ctx[kk][dt][qt] =
              __builtin_amdgcn_mfma_f32_16x16x32_bf16(vfr[dt], pfl, ctx[kk][dt][qt], 0, 0, 0);
        }
      }
    }
  }

  // ---- per-track: stash wave partials, combine 4 waves -> chunk partial
#pragma unroll
  for (int kk = 0; kk < 3; kk++) {
    __syncthreads(); // protect Vts/Qls (kk=0) or prior combine reads (kk>0)
    if (g == 0) {
#pragma unroll
      for (int qt = 0; qt < 2; qt++) {
        cmS[w * 32 + qt * 16 + l15] = mq[kk][qt];
        clS[w * 32 + qt * 16 + l15] = lsm[kk][qt];
      }
    }
#pragma unroll
    for (int dt = 0; dt < 4; dt++)
#pragma unroll
      for (int qt = 0; qt < 2; qt++) {
        f32x4 v = ctx[kk][dt][qt];
        int q = qt * 16 + l15;
        int dd = dt * 16 + g * 4;
#pragma unroll
        for (int r = 0; r < 4; r++) ctxc[(w * 32 + q) * 68 + dd + r] = v[r];
      }
    __syncthreads();
    {
      int q = tid >> 3, dg = tid & 7;
      float m0 = cmS[q], m1 = cmS[32 + q], m2 = cmS[64 + q], m3 = cmS[96 + q];
      float ms = fmaxf(fmaxf(m0, m1), fmaxf(m2, m3));
      float e0 = __expf(m0 - ms), e1 = __expf(m1 - ms);
      float e2 = __expf(m2 - ms), e3 = __expf(m3 - ms);
      float ls = e0 * clS[q] + e1 * clS[32 + q] + e2 * clS[64 + q] + e3 * clS[96 + q];
      int pbase = (((kk * 8 + b) * 8 + h) * 8 + c) * 32;
      size_t urow = (size_t)(pbase + q) * 64 + dg * 8;
#pragma unroll
      for (int half = 0; half < 2; half++) {
        int d0 = dg * 8 + half * 4;
        f4 acc = e0 * *(const f4*)&ctxc[q * 68 + d0] +
                 e1 * *(const f4*)&ctxc[(32 + q) * 68 + d0] +
                 e2 * *(const f4*)&ctxc[(64 + q) * 68 + d0] +
                 e3 * *(const f4*)&ctxc[(96 + q) * 68 + d0];
        *(f4*)&pu[urow + half * 4] = acc;
      }
      if (dg == 0) {
        pm[pbase + q] = ms;
        pl[pbase + q] = ls;
      }
    }
  }
}

// ---------------- 8. combine + output chain -------------------------------
__global__ __launch_bounds__(256) void out_chain(
    const float* __restrict__ pm, const float* __restrict__ pl,
    const float* __restrict__ pu, const float* __restrict__ Watt,
    const float* __restrict__ batt, const float* __restrict__ Wo,
    const float* __restrict__ bo, const float* __restrict__ gk,
    float* __restrict__ out) {
  __shared__ float Cs[8][512];
  __shared__ float T1[8][512];
  int tid = threadIdx.x;
  int r0 = blockIdx.x * 8;
  { // combine chunk partials -> ctx
    int ri = tid >> 5, hh = (tid >> 2) & 7, dq = tid & 3;
    int d0 = dq * 16;
    int r = r0 + ri;
    int k = r >> 8, b = (r >> 5) & 7, s = r & 31;
    int pb0 = ((((k * 8 + b) * 8 + hh) * 8) * 32) + s; // c=0
    float mstar = -3.0e38f;
#pragma unroll
    for (int cc = 0; cc < 8; cc++) mstar = fmaxf(mstar, pm[pb0 + cc * 32]);
    float ls = 0.f;
    f4 us[4];
#pragma unroll
    for (int t4 = 0; t4 < 4; t4++) us[t4] = (f4){0.f, 0.f, 0.f, 0.f};
#pragma unroll
    for (int cc = 0; cc < 8; cc++) {
      int pidx = pb0 + cc * 32;
      float wv = __expf(pm[pidx] - mstar);
      ls += wv * pl[pidx];
      const f4* up = (const f4*)&pu[(size_t)pidx * 64 + d0];
#pragma unroll
      for (int t4 = 0; t4 < 4; t4++) us[t4] += up[t4] * wv;
    }
    float inv = 1.f / ls;
#pragma unroll
    for (int t4 = 0; t4 < 4; t4++)
#pragma unroll
      for (int j = 0; j < 4; j++) Cs[ri][hh * 64 + d0 + t4 * 4 + j] = us[t4][j] * inv;
  }
  __syncthreads();
  int c0 = tid, c1 = tid + 256;
  { // T1 = Cs @ W_attn_out + b_attn_out
    float a0[8], a1[8];
#pragma unroll
    for (int i = 0; i < 8; i++) { a0[i] = 0.f; a1[i] = 0.f; }
#pragma unroll 4
    for (int l = 0; l < 512; l++) {
      float w0 = Watt[(size_t)l * 512 + c0];
      float w1 = Watt[(size_t)l * 512 + c1];
#pragma unroll
      for (int i = 0; i < 8; i++) {
        float z = Cs[i][l];
        a0[i] += z * w0;
        a1[i] += z * w1;
      }
    }
    float bb0 = batt[c0], bb1 = batt[c1];
#pragma unroll
    for (int i = 0; i < 8; i++) {
      T1[i][c0] = a0[i] + bb0;
      T1[i][c1] = a1[i] + bb1;
    }
  }
  __syncthreads();
  { // out = (T1 @ W_o + b_o) * gk, permuted to (b, k*32+s, d)
    float a0[8], a1[8];
#pragma unroll
    for (int i = 0; i < 8; i++) { a0[i] = 0.f; a1[i] = 0.f; }
#pragma unroll 4
    for (int l = 0; l < 512; l++) {
      float w0 = Wo[(size_t)l * 512 + c0];
      float w1 = Wo[(size_t)l * 512 + c1];
#pragma unroll
      for (int i = 0; i < 8; i++) {
        float z = T1[i][l];
        a0[i] += z * w0;
        a1[i] += z * w1;
      }
    }
    float bb0 = bo[c0], bb1 = bo[c1];
#pragma unroll
    for (int i = 0; i < 8; i++) {
      int r = r0 + i;
      int k = r >> 8, b = (r >> 5) & 7, s = r & 31;
      float g = gk[r];
      size_t orow = (size_t)(b * 96 + k * 32 + s) * 512;
      out[orow + c0] = (a0[i] + bb0) * g;
      out[orow + c1] = (a1[i] + bb1) * g;
    }
  }
}

// ---------------------------------------------------------------------------
extern "C" void kernel_launch(void* const* d_in, const int* in_sizes, int n_in,
                              void* d_out, int out_size, void* d_ws, size_t ws_size,
                              hipStream_t stream) {
  const float* proj = (const float*)d_in[0];
  const float* hctc = (const float*)d_in[1];
  const float* A = (const float*)d_in[2];
  const int* spikes = (const int*)d_in[3];
  const float* Wmem = (const float*)d_in[4];
  const float* bmem = (const float*)d_in[5];
  const float* Wkv = (const float*)d_in[6];
  const float* bkv = (const float*)d_in[7];
  const float* Wq = (const float*)d_in[8];
  const float* bq = (const float*)d_in[9];
  const float* Wqkv = (const float*)d_in[10];
  const float* bqkv = (const float*)d_in[11];
  const float* Watt = (const float*)d_in[12];
  const float* batt = (const float*)d_in[13];
  const float* Wo = (const float*)d_in[14];
  const float* bo = (const float*)d_in[15];
  float* out = (float*)d_out;
  (void)in_sizes; (void)n_in; (void)out_size; (void)ws_size;

  char* w = (char*)d_ws;
  bf16* projb = (bf16*)(w + 0);            //  67108864 B
  bf16* kvb   = (bf16*)(w + 67108864);     // 134217728 B
  bf16* w2t   = (bf16*)(w + 201326592);    //   1048576 B
  float* b2   = (float*)(w + 202375168);   //      4096 B
  int* spk    = (int*)(w + 202379264);     //      3072 B
  float* warr = (float*)(w + 202382336);   //     52224 B
  float* winv = (float*)(w + 202434560);   //      3072 B
  float* gk   = (float*)(w + 202437632);   //      3072 B
  float* Zb   = (float*)(w + 202440704);   //   1572864 B
  float* qws  = (float*)(w + 204013568);   //   1572864 B
  float* pm   = (float*)(w + 205586432);   //    196608 B
  float* pl   = (float*)(w + 205783040);   //    196608 B
  float* pu   = (float*)(w + 205979648);   //  12582912 B -> end 218562560

  prep_w2t<<<dim3(16, 8), 256, 0, stream>>>(Wmem, Wqkv, w2t);
  bias2_kernel<<<16, 256, 0, stream>>>(bmem, Wqkv, bqkv, b2);
  cvt_bf16<<<16384, 256, 0, stream>>>(proj, projb);
  kv_gemm<<<dim3(8, 512), 256, 0, stream>>>(projb, w2t, b2, kvb);
  topk_kernel<<<24, 128, 0, stream>>>(A, spikes, spk, warr, winv, gk);
  z_gather<<<768, 256, 0, stream>>>(hctc, spk, warr, winv, Zb);
  seed_chain<<<96, 256, 0, stream>>>(Zb, Wkv, bkv, Wq, bq, Wqkv, bqkv, qws);
  attn_kernel<<<512, 256, 0, stream>>>(kvb, qws, pm, pl, pu);
  out_chain<<<96, 256, 0, stream>>>(pm, pl, pu, Watt, batt, Wo, bo, gk, out);
}

// Round 4
// 958.065 us; speedup vs baseline: 1.4304x; 1.1744x over previous
//
#include <hip/hip_runtime.h>
#include <hip/hip_bf16.h>

// ---------------------------------------------------------------------------
// CTCBridgeSparseSlot on MI355X.
// Pipeline:
//   1. prep_w2t   : W2^T = (W_mem @ W_qkv[:,512:1536])^T  -> bf16 [1024][512]
//      bias2      : b2 = b_mem @ Wsub + b_qkv[512:1536]
//   2. cvt_bf16   : proj_feats f32 -> bf16
//   3. kv_gemm    : kv[65536][1024] = proj_bf16 @ W2 + b2  (bf16 MFMA)
//      prep_wt    : 7 weight mats -> transposed [col][k] hi/lo bf16
//                   (runs AFTER kv_gemm; wt buffers ALIAS the dead projb
//                    region to stay inside the proven 218562560 B footprint)
//   4. topk_kernel: per (k,b): window-mean scores, exact top-32
//   5. z_gather   : Z[768][512] weighted h_ctc window means (f32)
//   6. seed_mfma  : q = (tanh((Z@Wkv_k + b) @ W_q + b_q)) @ Wqh + bqh
//                   (MFMA hi/lo chain, 48 blocks x 512 thr)
//   7. attn_kernel: MFMA flash attention, 3 spike-tracks merged per block
//   8. out_mfma   : combine partials -> ctx -> @W_attn_out -> @W_o -> *gk
//                   (MFMA hi/lo chain)
// ---------------------------------------------------------------------------

#define T_LEN 8192
#define DMODEL 512
#define NROWS 768 // 3*8*32

typedef __hip_bfloat16 bf16;
typedef short s16x8 __attribute__((ext_vector_type(8)));
typedef short s16x4 __attribute__((ext_vector_type(4)));
typedef float f32x4 __attribute__((ext_vector_type(4)));
typedef float f4 __attribute__((ext_vector_type(4)));
typedef float f2 __attribute__((ext_vector_type(2)));
typedef int i32x4 __attribute__((ext_vector_type(4)));

typedef __attribute__((address_space(3))) void* lds_vp;
typedef const __attribute__((address_space(1))) void* gbl_cvp;

static __device__ __forceinline__ unsigned bf16rne(float f) {
  unsigned x = __builtin_bit_cast(unsigned, f);
  return (x + 0x7fffu + ((x >> 16) & 1u)) >> 16;
}
static __device__ __forceinline__ float bfval(unsigned u) {
  return __builtin_bit_cast(float, u << 16);
}
static __device__ __forceinline__ void hilo(float x, unsigned& h, unsigned& l) {
  h = bf16rne(x);
  l = bf16rne(x - bfval(h));
}

// ---------------- 1. combined weight prep ---------------------------------
__global__ __launch_bounds__(256) void prep_w2t(const float* __restrict__ Wmem,
                                                const float* __restrict__ Wqkv,
                                                bf16* __restrict__ w2t) {
  __shared__ __align__(16) float As[16][68]; // As[l][j] = Wqkv[l0+l][512+j0+j]
  __shared__ __align__(16) float Bs[16][68]; // Bs[l][i] = Wmem[i0+i][l0+l]
  int tid = threadIdx.x;
  int j0 = blockIdx.x * 64, i0 = blockIdx.y * 64;
  int ty = tid >> 4, tx = tid & 15;
  float c[4][4];
#pragma unroll
  for (int a = 0; a < 4; a++)
#pragma unroll
    for (int b = 0; b < 4; b++) c[a][b] = 0.f;

  for (int l0 = 0; l0 < 512; l0 += 16) {
    __syncthreads();
    {
      int l = tid >> 4, j4 = (tid & 15) * 4;
      f4 v = *(const f4*)&Wqkv[(size_t)(l0 + l) * 1536 + 512 + j0 + j4];
      *(f4*)&As[l][j4] = v;
    }
    {
      int i = tid >> 2, l4 = (tid & 3) * 4;
      f4 v = *(const f4*)&Wmem[(size_t)(i0 + i) * 512 + l0 + l4];
      Bs[l4 + 0][i] = v[0];
      Bs[l4 + 1][i] = v[1];
      Bs[l4 + 2][i] = v[2];
      Bs[l4 + 3][i] = v[3];
    }
    __syncthreads();
#pragma unroll
    for (int l = 0; l < 16; l++) {
      f4 a = *(f4*)&As[l][ty * 4];
      f4 b = *(f4*)&Bs[l][tx * 4];
#pragma unroll
      for (int jj = 0; jj < 4; jj++)
#pragma unroll
        for (int ii = 0; ii < 4; ii++) c[jj][ii] += a[jj] * b[ii];
    }
  }
#pragma unroll
  for (int jj = 0; jj < 4; jj++)
#pragma unroll
    for (int ii = 0; ii < 4; ii++)
      w2t[(size_t)(j0 + ty * 4 + jj) * 512 + i0 + tx * 4 + ii] =
          __float2bfloat16(c[jj][ii]);
}

__global__ __launch_bounds__(256) void bias2_kernel(const float* __restrict__ bmem,
                                                    const float* __restrict__ Wqkv,
                                                    const float* __restrict__ bqkv,
                                                    float* __restrict__ b2) {
  __shared__ float red[4][64];
  int j0 = blockIdx.x * 64;
  int jc = threadIdx.x & 63, lp = threadIdx.x >> 6;
  int j = j0 + jc;
  float acc = 0.f;
  for (int l = lp * 128; l < lp * 128 + 128; l++)
    acc += bmem[l] * Wqkv[(size_t)l * 1536 + 512 + j];
  red[lp][jc] = acc;
  __syncthreads();
  if (threadIdx.x < 64) {
    float s = red[0][jc] + red[1][jc] + red[2][jc] + red[3][jc];
    b2[j0 + jc] = s + bqkv[512 + j0 + jc];
  }
}

// ---- prep_wt: transpose 7 [512][512] weights to [col][k] hi/lo bf16 ------
// jobs: 0..2 = Wkv[k][:, :512] (ld 1024), 3 = Wq (512), 4 = Wqkv[:, :512]
// (ld 1536), 5 = Watt (512), 6 = Wo (512).
__global__ __launch_bounds__(256) void prep_wt(const float* __restrict__ Wkv,
                                               const float* __restrict__ Wq,
                                               const float* __restrict__ Wqkv,
                                               const float* __restrict__ Watt,
                                               const float* __restrict__ Wo,
                                               short* __restrict__ wt_hi,
                                               short* __restrict__ wt_lo) {
  __shared__ float Ls[64][65];
  int tid = threadIdx.x;
  int bx = blockIdx.x, by = blockIdx.y, bz = blockIdx.z;
  const float* src;
  int ld;
  if (bz < 3) { src = Wkv + (size_t)bz * 512 * 1024; ld = 1024; }
  else if (bz == 3) { src = Wq; ld = 512; }
  else if (bz == 4) { src = Wqkv; ld = 1536; }
  else if (bz == 5) { src = Watt; ld = 512; }
  else { src = Wo; ld = 512; }
  int t63 = tid & 63, t4 = tid >> 6;
#pragma unroll
  for (int p = 0; p < 16; p++) {
    int row = p * 4 + t4;
    Ls[row][t63] = src[(size_t)(by * 64 + row) * ld + bx * 64 + t63];
  }
  __syncthreads();
#pragma unroll
  for (int p = 0; p < 16; p++) {
    int cc = p * 4 + t4; // src col (= dst row)
    float v = Ls[t63][cc];
    unsigned h, l;
    hilo(v, h, l);
    size_t idx = (size_t)(bz * 512 + bx * 64 + cc) * 512 + by * 64 + t63;
    wt_hi[idx] = (short)h;
    wt_lo[idx] = (short)l;
  }
}

// ---------------- 2. proj -> bf16 -----------------------------------------
__global__ __launch_bounds__(256) void cvt_bf16(const float* __restrict__ x,
                                                bf16* __restrict__ y) {
  int i = blockIdx.x * 256 + threadIdx.x; // 8 elems each, n=33554432
  const f4* p = (const f4*)x;
  f4 a = p[(size_t)i * 2], b = p[(size_t)i * 2 + 1];
  __align__(16) bf16 o[8];
  o[0] = __float2bfloat16(a[0]);
  o[1] = __float2bfloat16(a[1]);
  o[2] = __float2bfloat16(a[2]);
  o[3] = __float2bfloat16(a[3]);
  o[4] = __float2bfloat16(b[0]);
  o[5] = __float2bfloat16(b[1]);
  o[6] = __float2bfloat16(b[2]);
  o[7] = __float2bfloat16(b[3]);
  ((f4*)y)[i] = *(f4*)o;
}

// ---------------- 3. big GEMM: kv = proj_bf16 @ W2 + b2 (bf16 MFMA) -------
__global__ __launch_bounds__(256) void kv_gemm(const bf16* __restrict__ A,
                                               const bf16* __restrict__ Bt,
                                               const float* __restrict__ bias,
                                               bf16* __restrict__ C) {
  __shared__ __align__(16) char sm[16384];
  bf16* As = (bf16*)sm;           // [128][32]
  bf16* Bs = (bf16*)(sm + 8192);  // [128][32]
  int tid = threadIdx.x;
  int lane = tid & 63, wave = tid >> 6;
  int wm = wave & 1, wn = wave >> 1;
  int m0 = blockIdx.y * 128, n0 = blockIdx.x * 128;
  int l15 = lane & 15, g = lane >> 4;
  f32x4 acc[4][4];
#pragma unroll
  for (int mi = 0; mi < 4; mi++)
#pragma unroll
    for (int ni = 0; ni < 4; ni++) acc[mi][ni] = (f32x4){0.f, 0.f, 0.f, 0.f};

  int arow = tid >> 2, akq = (tid & 3) * 8;
  for (int k0 = 0; k0 < 512; k0 += 32) {
    __syncthreads();
#pragma unroll
    for (int i = 0; i < 2; i++) {
      const bf16* ga = &A[(size_t)(m0 + i * 64 + arow) * 512 + k0 + akq];
      const bf16* gb = &Bt[(size_t)(n0 + i * 64 + arow) * 512 + k0 + akq];
      __builtin_amdgcn_global_load_lds((gbl_cvp)ga,
                                       (lds_vp)(sm + (i * 256 + wave * 64) * 16),
                                       16, 0, 0);
      __builtin_amdgcn_global_load_lds((gbl_cvp)gb,
                                       (lds_vp)(sm + 8192 + (i * 256 + wave * 64) * 16),
                                       16, 0, 0);
    }
    __syncthreads();
    s16x8 af[4], bfr[4];
#pragma unroll
    for (int mi = 0; mi < 4; mi++)
      af[mi] = *(s16x8*)&As[(wm * 64 + mi * 16 + l15) * 32 + g * 8];
#pragma unroll
    for (int ni = 0; ni < 4; ni++)
      bfr[ni] = *(s16x8*)&Bs[(wn * 64 + ni * 16 + l15) * 32 + g * 8];
#pragma unroll
    for (int mi = 0; mi < 4; mi++)
#pragma unroll
      for (int ni = 0; ni < 4; ni++)
        acc[mi][ni] = __builtin_amdgcn_mfma_f32_16x16x32_bf16(bfr[ni], af[mi],
                                                              acc[mi][ni], 0, 0, 0);
  }

  // epilogue: 4 passes (mi); stage [32][136] bf16 tile in LDS, 16B stores
  short* ep = (short*)sm;
  int band = wm * 16 + l15;
#pragma unroll
  for (int mi = 0; mi < 4; mi++) {
    __syncthreads();
#pragma unroll
    for (int ni = 0; ni < 4; ni++) {
      int c0 = wn * 64 + ni * 16 + g * 4;
      f4 bv = *(const f4*)&bias[n0 + c0];
      f32x4 v = acc[mi][ni];
      __align__(8) bf16 pk[4];
#pragma unroll
      for (int r = 0; r < 4; r++) pk[r] = __float2bfloat16(v[r] + bv[r]);
      *(s16x4*)&ep[band * 136 + c0] = *(s16x4*)pk;
    }
    __syncthreads();
#pragma unroll
    for (int it = 0; it < 2; it++) {
      int cidx = it * 256 + tid;
      int brow = cidx >> 4, ch = cidx & 15;
      s16x8 val = *(s16x8*)&ep[brow * 136 + ch * 8];
      int row = m0 + (brow >> 4) * 64 + mi * 16 + (brow & 15);
      *(s16x8*)&C[(size_t)row * 1024 + n0 + ch * 8] = val;
    }
  }
}

// ---------------- 4. top-k spike selection --------------------------------
__global__ __launch_bounds__(128) void topk_kernel(const float* __restrict__ A,
                                                   const int* __restrict__ spikes,
                                                   int* __restrict__ spk_out,
                                                   float* __restrict__ w_out,
                                                   float* __restrict__ winv_out,
                                                   float* __restrict__ gk_out) {
  int kb = blockIdx.x; // (k*8+b) in [0,24)
  int i = threadIdx.x; // [0,128)
  const float* Ab = A + (size_t)kb * T_LEN;
  __shared__ float s_sc[128];
  __shared__ int s_sp[128];
  __shared__ int s_sel[32];
  int t0 = spikes[kb * 128 + i];
  s_sp[i] = t0;
  float sum = 0.f;
  int cnt = 0;
#pragma unroll
  for (int o = -8; o <= 8; o++) {
    int t = t0 + o;
    if (t >= 0 && t < T_LEN) { sum += Ab[t]; cnt++; }
  }
  float sc = (t0 >= 0 && t0 < T_LEN) ? (sum / (float)max(cnt, 1)) : -1e9f;
  s_sc[i] = sc;
  __syncthreads();
  float sci = s_sc[i];
  int rank = 0;
  for (int j = 0; j < 128; j++) {
    float scj = s_sc[j];
    if (scj > sci || (scj == sci && j < i)) rank++;
  }
  if (rank < 32) s_sel[rank] = i;
  __syncthreads();
  if (i < 32) {
    int sel = s_sel[i];
    int spkv = s_sp[sel];
    float conf = s_sc[sel];
    int r = kb * 32 + i;
    spk_out[r] = spkv;
    bool vmask = (spkv >= 0 && spkv < T_LEN);
    float wsum = 0.f;
#pragma unroll
    for (int o = 0; o < 17; o++) {
      int t = spkv + o - 8;
      bool v = vmask && (t >= 0) && (t < T_LEN);
      int tc = min(max(t, 0), T_LEN - 1);
      float off = (float)(o - 8) * 0.25f;
      float g = expf(-0.5f * off * off);
      float wv = v ? g * Ab[tc] : 0.f;
      wsum += wv;
      w_out[r * 17 + o] = wv;
    }
    winv_out[r] = 1.f / (wsum + 1e-6f);
    gk_out[r] = vmask ? (1.f / (1.f + expf(-2.f * conf))) : 0.f;
  }
}

// ---------------- 5. Z gather ---------------------------------------------
__global__ __launch_bounds__(256) void z_gather(const float* __restrict__ hctc,
                                                const int* __restrict__ spk,
                                                const float* __restrict__ warr,
                                                const float* __restrict__ winv,
                                                float* __restrict__ Z) {
  int r = blockIdx.x; // [0,768)
  int tid = threadIdx.x;
  int kb = r >> 5;
  const float* h = hctc + (size_t)kb * T_LEN * DMODEL;
  int sp = spk[r];
  float wi = winv[r];
  float acc0 = 0.f, acc1 = 0.f;
#pragma unroll
  for (int o = 0; o < 17; o++) {
    float wv = warr[r * 17 + o];
    int t = min(max(sp + o - 8, 0), T_LEN - 1);
    const float* hp = h + (size_t)t * DMODEL;
    acc0 += wv * hp[tid];
    acc1 += wv * hp[tid + 256];
  }
  Z[(size_t)r * DMODEL + tid] = acc0 * wi;
  Z[(size_t)r * DMODEL + tid + 256] = acc1 * wi;
}

// ---------------- 6. seed chain (MFMA hi/lo) ------------------------------
// 48 blocks x 512 threads; block = 16 rows; wave handles 64 output cols.
// activations kept as hi/lo bf16 in LDS [row][520].
__global__ __launch_bounds__(512) void seed_mfma(
    const float* __restrict__ Z, const short* __restrict__ wt_hi,
    const short* __restrict__ wt_lo, const float* __restrict__ bkv,
    const float* __restrict__ bq, const float* __restrict__ bqkv,
    float* __restrict__ qout) {
  __shared__ short cb[4][16][520]; // 0,1 = A hi/lo ; 2,3 = B hi/lo
  int tid = threadIdx.x;
  int rb = blockIdx.x * 16;
  int trk = rb >> 8;
  int lane = tid & 63, wave = tid >> 6;
  int l15 = lane & 15, g = lane >> 4;
  int wbase = wave * 64;

  // load Z rows -> hi/lo LDS
#pragma unroll
  for (int i = 0; i < 16; i++) {
    int idx = i * 512 + tid;
    int row = idx >> 9, col = idx & 511;
    float v = Z[(size_t)rb * 512 + idx];
    unsigned h, l;
    hilo(v, h, l);
    cb[0][row][col] = (short)h;
    cb[1][row][col] = (short)l;
  }
  __syncthreads();

#pragma unroll
  for (int stage = 0; stage < 3; stage++) {
    int sh = (stage & 1) ? 2 : 0; // src hi buf
    int dh = (stage & 1) ? 0 : 2; // dst hi buf
    int job = (stage == 0) ? trk : (stage == 1 ? 3 : 4);
    const float* bias = (stage == 0) ? (bkv + trk * 1024) : (stage == 1 ? bq : bqkv);
    f32x4 acc[4];
#pragma unroll
    for (int nt = 0; nt < 4; nt++) acc[nt] = (f32x4){0.f, 0.f, 0.f, 0.f};
    for (int k0 = 0; k0 < 512; k0 += 32) {
      s16x8 ah = *(const s16x8*)&cb[sh][l15][k0 + g * 8];
      s16x8 al = *(const s16x8*)&cb[sh + 1][l15][k0 + g * 8];
#pragma unroll
      for (int nt = 0; nt < 4; nt++) {
        size_t wrow = (size_t)(job * 512 + wbase + nt * 16 + l15) * 512 + k0 + g * 8;
        s16x8 wh = *(const s16x8*)&wt_hi[wrow];
        s16x8 wl = *(const s16x8*)&wt_lo[wrow];
        acc[nt] = __builtin_amdgcn_mfma_f32_16x16x32_bf16(wh, ah, acc[nt], 0, 0, 0);
        acc[nt] = __builtin_amdgcn_mfma_f32_16x16x32_bf16(wh, al, acc[nt], 0, 0, 0);
        acc[nt] = __builtin_amdgcn_mfma_f32_16x16x32_bf16(wl, ah, acc[nt], 0, 0, 0);
      }
    }
    // lane holds out[row=l15][cols wbase + nt*16 + g*4 + r]
    if (stage < 2) {
      __syncthreads(); // prior stage's src reads done before overwrite
#pragma unroll
      for (int nt = 0; nt < 4; nt++) {
        int co0 = wbase + nt * 16 + g * 4;
        f4 bb = *(const f4*)&bias[co0];
        s16x4 h4, l4;
#pragma unroll
        for (int r = 0; r < 4; r++) {
          float v = acc[nt][r] + bb[r];
          if (stage == 1) v = tanhf(v);
          unsigned h, l;
          hilo(v, h, l);
          h4[r] = (short)h;
          l4[r] = (short)l;
        }
        *(s16x4*)&cb[dh][l15][co0] = h4;
        *(s16x4*)&cb[dh + 1][l15][co0] = l4;
      }
      __syncthreads();
    } else {
#pragma unroll
      for (int nt = 0; nt < 4; nt++) {
        int co0 = wbase + nt * 16 + g * 4;
        f4 bb = *(const f4*)&bias[co0];
        f4 v;
#pragma unroll
        for (int r = 0; r < 4; r++) v[r] = acc[nt][r] + bb[r];
        *(f4*)&qout[(size_t)(rb + l15) * 512 + co0] = v;
      }
    }
  }
}

// ---------------- 7. attention (MFMA flash, 3 tracks merged) --------------
__global__ __launch_bounds__(256) void attn_kernel(const bf16* __restrict__ kv,
                                                   const float* __restrict__ qws,
                                                   float* __restrict__ pm,
                                                   float* __restrict__ pl,
                                                   float* __restrict__ pu) {
  __shared__ __align__(16) char smem[40960];
  short* Vts = (short*)smem;            // loop: [4][2048] per-wave V^T swizzled
  short* Qls = (short*)(smem + 16384);  // loop: [12 slots][2 hl][64 lane][8]
  float* ctxc = (float*)smem;           // combine: [4][32][68]
  float* cmS = (float*)(smem + 34816);  // combine: [4][32]
  float* clS = (float*)(smem + 35328);  // combine: [4][32]

  int tid = threadIdx.x;
  int w = tid >> 6, lane = tid & 63;
  int l15 = lane & 15, g = lane >> 4;
  int bx = blockIdx.x;
  int c = bx & 7, h = (bx >> 3) & 7, b = bx >> 6; // 512 blocks
  const short* kvS = (const short*)kv;
  int hoff = h * 64;
  int rowK = b * T_LEN + c * 1024 + w * 256;

  // ---- Q staging into LDS: slot = kk*4 + qt*2 + ds, hi/lo bf16 frags
#pragma unroll
  for (int p = 0; p < 3; p++) {
    int slot = p * 4 + (tid >> 6);
    int kk = slot >> 2, qt = (slot >> 1) & 1, ds = slot & 1;
    int ln = tid & 63;
    int sl15 = ln & 15, sg = ln >> 4;
    const float* qp = qws + (size_t)((kk * 8 + b) * 32 + qt * 16 + sl15) * 512 +
                      hoff + ds * 32 + sg * 8;
    f4 x = *(const f4*)qp;
    f4 y = *(const f4*)(qp + 4);
    x *= 0.125f;
    y *= 0.125f;
    s16x8 hi, lo;
#pragma unroll
    for (int j = 0; j < 4; j++) {
      unsigned hb, lb;
      hilo(x[j], hb, lb);
      hi[j] = (short)hb;
      lo[j] = (short)lb;
      hilo(y[j], hb, lb);
      hi[4 + j] = (short)hb;
      lo[4 + j] = (short)lb;
    }
    *(s16x8*)&Qls[((slot * 2 + 0) * 64 + ln) * 8] = hi;
    *(s16x8*)&Qls[((slot * 2 + 1) * 64 + ln) * 8] = lo;
  }
  __syncthreads();

  float mq[3][2];
  float lsm[3][2];
  f32x4 ctx[3][4][2]; // [track][dtile][qtile]
#pragma unroll
  for (int kk = 0; kk < 3; kk++)
#pragma unroll
    for (int qt = 0; qt < 2; qt++) {
      mq[kk][qt] = -3.0e38f;
      lsm[kk][qt] = 0.f;
    }
#pragma unroll
  for (int kk = 0; kk < 3; kk++)
#pragma unroll
    for (int dt = 0; dt < 4; dt++)
#pragma unroll
      for (int qt = 0; qt < 2; qt++) ctx[kk][dt][qt] = (f32x4){0.f, 0.f, 0.f, 0.f};

  // bpermute byte-indices for P^T frag assembly
  int a0 = (l15 + (((2 * g) & 3) << 4)) << 2;
  int a1 = a0 + 64;

  for (int st = 0; st < 8; st++) {
    int tbase = st * 32;
    // ---- K A-frags direct from global: kf[Mtile][dslice]
    s16x8 kf[2][2];
#pragma unroll
    for (int mt = 0; mt < 2; mt++) {
      size_t krow = (size_t)(rowK + tbase + mt * 16 + l15) * 1024 + hoff;
#pragma unroll
      for (int ds = 0; ds < 2; ds++)
        kf[mt][ds] = *(const s16x8*)(kvS + krow + ds * 32 + g * 8);
    }
    // ---- V loads + transpose-scatter into per-wave swizzled LDS
    {
      s16x8 vv[4];
#pragma unroll
      for (int i = 0; i < 4; i++)
        vv[i] = *(const s16x8*)(kvS +
                                (size_t)(rowK + tbase + i * 8 + (lane >> 3)) * 1024 +
                                512 + hoff + (lane & 7) * 8);
#pragma unroll
      for (int i = 0; i < 4; i++) {
        int tk = i * 8 + (lane >> 3);
        int dbase = (lane & 7) * 8;
#pragma unroll
        for (int j = 0; j < 8; j++) {
          int d = dbase + j;
          Vts[w * 2048 + d * 32 + (tk & 7) + ((i ^ ((d >> 3) & 3)) << 3)] = vv[i][j];
        }
      }
    }
    // ---- V^T A-frags (LDS ops in-order within wave; no barrier needed)
    s16x8 vfr[4];
#pragma unroll
    for (int dt = 0; dt < 4; dt++) {
      int d = dt * 16 + l15;
      vfr[dt] = *(const s16x8*)&Vts[w * 2048 + d * 32 + ((g ^ ((d >> 3) & 3)) << 3)];
    }
    // ---- per spike-track: S, softmax, PV
#pragma unroll
    for (int kk = 0; kk < 3; kk++) {
      s16x8 qf[2][2][2];
#pragma unroll
      for (int qt = 0; qt < 2; qt++)
#pragma unroll
        for (int ds = 0; ds < 2; ds++)
#pragma unroll
          for (int hl = 0; hl < 2; hl++)
            qf[qt][ds][hl] =
                *(const s16x8*)&Qls[(((kk * 4 + qt * 2 + ds) * 2 + hl) * 64 + lane) * 8];
      // S^T = K @ Q^T (hi+lo accumulate)
      f32x4 sa[2][2];
#pragma unroll
      for (int mt = 0; mt < 2; mt++)
#pragma unroll
        for (int qt = 0; qt < 2; qt++) {
          f32x4 acc = (f32x4){0.f, 0.f, 0.f, 0.f};
          acc = __builtin_amdgcn_mfma_f32_16x16x32_bf16(kf[mt][0], qf[qt][0][0], acc, 0, 0, 0);
          acc = __builtin_amdgcn_mfma_f32_16x16x32_bf16(kf[mt][0], qf[qt][0][1], acc, 0, 0, 0);
          acc = __builtin_amdgcn_mfma_f32_16x16x32_bf16(kf[mt][1], qf[qt][1][0], acc, 0, 0, 0);
          acc = __builtin_amdgcn_mfma_f32_16x16x32_bf16(kf[mt][1], qf[qt][1][1], acc, 0, 0, 0);
          sa[mt][qt] = acc;
        }
#pragma unroll
      for (int qt = 0; qt < 2; qt++) {
        f32x4 s0 = sa[0][qt], s1 = sa[1][qt];
        float tm = fmaxf(fmaxf(fmaxf(s0[0], s0[1]), fmaxf(s0[2], s0[3])),
                         fmaxf(fmaxf(s1[0], s1[1]), fmaxf(s1[2], s1[3])));
        tm = fmaxf(tm, __shfl_xor(tm, 16, 64));
        tm = fmaxf(tm, __shfl_xor(tm, 32, 64));
        float mn = fmaxf(mq[kk][qt], tm);
        float p0[4], p1[4];
        float ps = 0.f;
#pragma unroll
        for (int j = 0; j < 4; j++) {
          p0[j] = __expf(s0[j] - mn);
          p1[j] = __expf(s1[j] - mn);
          ps += p0[j] + p1[j];
        }
        ps += __shfl_xor(ps, 16, 64);
        ps += __shfl_xor(ps, 32, 64);
        float sc = __expf(mq[kk][qt] - mn);
        lsm[kk][qt] = lsm[kk][qt] * sc + ps;
        mq[kk][qt] = mn;
#pragma unroll
        for (int dt = 0; dt < 4; dt++) ctx[kk][dt][qt] *= sc;
        unsigned hh[8], ll[8];
#pragma unroll
        for (int j = 0; j < 4; j++) {
          hilo(p0[j], hh[j], ll[j]);
          hilo(p1[j], hh[4 + j], ll[4 + j]);
        }
        unsigned dh0 = hh[0] | (hh[1] << 16), dh1 = hh[2] | (hh[3] << 16);
        unsigned dh2 = hh[4] | (hh[5] << 16), dh3 = hh[6] | (hh[7] << 16);
        unsigned dl0 = ll[0] | (ll[1] << 16), dl1 = ll[2] | (ll[3] << 16);
        unsigned dl2 = ll[4] | (ll[5] << 16), dl3 = ll[6] | (ll[7] << 16);
        int x0 = __builtin_amdgcn_ds_bpermute(a0, (int)dh0);
        int x1 = __builtin_amdgcn_ds_bpermute(a0, (int)dh1);
        int x2 = __builtin_amdgcn_ds_bpermute(a0, (int)dh2);
        int x3 = __builtin_amdgcn_ds_bpermute(a0, (int)dh3);
        int y0 = __builtin_amdgcn_ds_bpermute(a1, (int)dh0);
        int y1 = __builtin_amdgcn_ds_bpermute(a1, (int)dh1);
        int y2 = __builtin_amdgcn_ds_bpermute(a1, (int)dh2);
        int y3 = __builtin_amdgcn_ds_bpermute(a1, (int)dh3);
        i32x4 fh;
        if (g < 2)
          fh = (i32x4){x0, x1, y0, y1};
        else
          fh = (i32x4){x2, x3, y2, y3};
        x0 = __builtin_amdgcn_ds_bpermute(a0, (int)dl0);
        x1 = __builtin_amdgcn_ds_bpermute(a0, (int)dl1);
        x2 = __builtin_amdgcn_ds_bpermute(a0, (int)dl2);
        x3 = __builtin_amdgcn_ds_bpermute(a0, (int)dl3);
        y0 = __builtin_amdgcn_ds_bpermute(a1, (int)dl0);
        y1 = __builtin_amdgcn_ds_bpermute(a1, (int)dl1);
        y2 = __builtin_amdgcn_ds_bpermute(a1, (int)dl2);
        y3 = __builtin_amdgcn_ds_bpermute(a1, (int)dl3);
        i32x4 fl;
        if (g < 2)
          fl = (i32x4){x0, x1, y0, y1};
        else
          fl = (i32x4){x2, x3, y2, y3};
        s16x8 pfh = __builtin_bit_cast(s16x8, fh);
        s16x8 pfl = __builtin_bit_cast(s16x8, fl);
#pragma unroll
        for (int dt = 0; dt < 4; dt++) {
          ctx[kk][dt][qt] =
              __builtin_amdgcn_mfma_f32_16x16x32_bf16(vfr[dt], pfh, ctx[kk][dt][qt], 0, 0, 0);
          ctx[kk][dt][qt] =
              __builtin_amdgcn_mfma_f32_16x16x32_bf16(vfr[dt], pfl, ctx[kk][dt][qt], 0, 0, 0);
        }
      }
    }
  }

  // ---- per-track: stash wave partials, combine 4 waves -> chunk partial
#pragma unroll
  for (int kk = 0; kk < 3; kk++) {
    __syncthreads(); // protect Vts/Qls (kk=0) or prior combine reads (kk>0)
    if (g == 0) {
#pragma unroll
      for (int qt = 0; qt < 2; qt++) {
        cmS[w * 32 + qt * 16 + l15] = mq[kk][qt];
        clS[w * 32 + qt * 16 + l15] = lsm[kk][qt];
      }
    }
#pragma unroll
    for (int dt = 0; dt < 4; dt++)
#pragma unroll
      for (int qt = 0; qt < 2; qt++) {
        f32x4 v = ctx[kk][dt][qt];
        int q = qt * 16 + l15;
        int dd = dt * 16 + g * 4;
#pragma unroll
        for (int r = 0; r < 4; r++) ctxc[(w * 32 + q) * 68 + dd + r] = v[r];
      }
    __syncthreads();
    {
      int q = tid >> 3, dg = tid & 7;
      float m0 = cmS[q], m1 = cmS[32 + q], m2 = cmS[64 + q], m3 = cmS[96 + q];
      float ms = fmaxf(fmaxf(m0, m1), fmaxf(m2, m3));
      float e0 = __expf(m0 - ms), e1 = __expf(m1 - ms);
      float e2 = __expf(m2 - ms), e3 = __expf(m3 - ms);
      float ls = e0 * clS[q] + e1 * clS[32 + q] + e2 * clS[64 + q] + e3 * clS[96 + q];
      int pbase = (((kk * 8 + b) * 8 + h) * 8 + c) * 32;
      size_t urow = (size_t)(pbase + q) * 64 + dg * 8;
#pragma unroll
      for (int half = 0; half < 2; half++) {
        int d0 = dg * 8 + half * 4;
        f4 acc = e0 * *(const f4*)&ctxc[q * 68 + d0] +
                 e1 * *(const f4*)&ctxc[(32 + q) * 68 + d0] +
                 e2 * *(const f4*)&ctxc[(64 + q) * 68 + d0] +
                 e3 * *(const f4*)&ctxc[(96 + q) * 68 + d0];
        *(f4*)&pu[urow + half * 4] = acc;
      }
      if (dg == 0) {
        pm[pbase + q] = ms;
        pl[pbase + q] = ls;
      }
    }
  }
}

// ---------------- 8. combine + output chain (MFMA hi/lo) ------------------
__global__ __launch_bounds__(512) void out_mfma(
    const float* __restrict__ pm, const float* __restrict__ pl,
    const float* __restrict__ pu, const short* __restrict__ wt_hi,
    const short* __restrict__ wt_lo, const float* __restrict__ batt,
    const float* __restrict__ bo, const float* __restrict__ gk,
    float* __restrict__ out) {
  __shared__ short cb[4][16][520];
  int tid = threadIdx.x;
  int rb = blockIdx.x * 16;
  int lane = tid & 63, wave = tid >> 6;
  int l15 = lane & 15, g = lane >> 4;
  int wbase = wave * 64;

  { // combine chunk partials -> ctx (hi/lo into cb[0],cb[1])
    int ri = tid >> 5, t32 = tid & 31;
    int hh = t32 >> 2, dq = t32 & 3;
    int d0 = dq * 16;
    int r = rb + ri;
    int kk = r >> 8, b = (r >> 5) & 7, s = r & 31;
    int pb0 = ((((kk * 8 + b) * 8 + hh) * 8) * 32) + s; // c=0
    float mstar = -3.0e38f;
#pragma unroll
    for (int cc = 0; cc < 8; cc++) mstar = fmaxf(mstar, pm[pb0 + cc * 32]);
    float ls = 0.f;
    f4 us[4];
#pragma unroll
    for (int t4 = 0; t4 < 4; t4++) us[t4] = (f4){0.f, 0.f, 0.f, 0.f};
#pragma unroll
    for (int cc = 0; cc < 8; cc++) {
      int pidx = pb0 + cc * 32;
      float wv = __expf(pm[pidx] - mstar);
      ls += wv * pl[pidx];
      const f4* up = (const f4*)&pu[(size_t)pidx * 64 + d0];
#pragma unroll
      for (int t4 = 0; t4 < 4; t4++) us[t4] += up[t4] * wv;
    }
    float inv = 1.f / ls;
#pragma unroll
    for (int t4 = 0; t4 < 4; t4++)
#pragma unroll
      for (int j = 0; j < 4; j++) {
        float v = us[t4][j] * inv;
        unsigned h, l;
        hilo(v, h, l);
        int col = hh * 64 + d0 + t4 * 4 + j;
        cb[0][ri][col] = (short)h;
        cb[1][ri][col] = (short)l;
      }
  }
  __syncthreads();

  // stage 1: @ Watt (job 5) -> cb[2],cb[3]
  {
    f32x4 acc[4];
#pragma unroll
    for (int nt = 0; nt < 4; nt++) acc[nt] = (f32x4){0.f, 0.f, 0.f, 0.f};
    for (int k0 = 0; k0 < 512; k0 += 32) {
      s16x8 ah = *(const s16x8*)&cb[0][l15][k0 + g * 8];
      s16x8 al = *(const s16x8*)&cb[1][l15][k0 + g * 8];
#pragma unroll
      for (int nt = 0; nt < 4; nt++) {
        size_t wrow = (size_t)(5 * 512 + wbase + nt * 16 + l15) * 512 + k0 + g * 8;
        s16x8 wh = *(const s16x8*)&wt_hi[wrow];
        s16x8 wl = *(const s16x8*)&wt_lo[wrow];
        acc[nt] = __builtin_amdgcn_mfma_f32_16x16x32_bf16(wh, ah, acc[nt], 0, 0, 0);
        acc[nt] = __builtin_amdgcn_mfma_f32_16x16x32_bf16(wh, al, acc[nt], 0, 0, 0);
        acc[nt] = __builtin_amdgcn_mfma_f32_16x16x32_bf16(wl, ah, acc[nt], 0, 0, 0);
      }
    }
    __syncthreads();
#pragma unroll
    for (int nt = 0; nt < 4; nt++) {
      int co0 = wbase + nt * 16 + g * 4;
      f4 bb = *(const f4*)&batt[co0];
      s16x4 h4, l4;
#pragma unroll
      for (int r = 0; r < 4; r++) {
        float v = acc[nt][r] + bb[r];
        unsigned h, l;
        hilo(v, h, l);
        h4[r] = (short)h;
        l4[r] = (short)l;
      }
      *(s16x4*)&cb[2][l15][co0] = h4;
      *(s16x4*)&cb[3][l15][co0] = l4;
    }
    __syncthreads();
  }

  // stage 2: @ Wo (job 6), gate gk, permuted store
  {
    f32x4 acc[4];
#pragma unroll
    for (int nt = 0; nt < 4; nt++) acc[nt] = (f32x4){0.f, 0.f, 0.f, 0.f};
    for (int k0 = 0; k0 < 512; k0 += 32) {
      s16x8 ah = *(const s16x8*)&cb[2][l15][k0 + g * 8];
      s16x8 al = *(const s16x8*)&cb[3][l15][k0 + g * 8];
#pragma unroll
      for (int nt = 0; nt < 4; nt++) {
        size_t wrow = (size_t)(6 * 512 + wbase + nt * 16 + l15) * 512 + k0 + g * 8;
        s16x8 wh = *(const s16x8*)&wt_hi[wrow];
        s16x8 wl = *(const s16x8*)&wt_lo[wrow];
        acc[nt] = __builtin_amdgcn_mfma_f32_16x16x32_bf16(wh, ah, acc[nt], 0, 0, 0);
        acc[nt] = __builtin_amdgcn_mfma_f32_16x16x32_bf16(wh, al, acc[nt], 0, 0, 0);
        acc[nt] = __builtin_amdgcn_mfma_f32_16x16x32_bf16(wl, ah, acc[nt], 0, 0, 0);
      }
    }
    int r = rb + l15;
    int kk = r >> 8, b = (r >> 5) & 7, s = r & 31;
    float gv = gk[r];
    size_t orow = (size_t)(b * 96 + kk * 32 + s) * 512;
#pragma unroll
    for (int nt = 0; nt < 4; nt++) {
      int co0 = wbase + nt * 16 + g * 4;
      f4 bb = *(const f4*)&bo[co0];
      f4 v;
#pragma unroll
      for (int r4 = 0; r4 < 4; r4++) v[r4] = (acc[nt][r4] + bb[r4]) * gv;
      *(f4*)&out[orow + co0] = v;
    }
  }
}

// ---------------------------------------------------------------------------
extern "C" void kernel_launch(void* const* d_in, const int* in_sizes, int n_in,
                              void* d_out, int out_size, void* d_ws, size_t ws_size,
                              hipStream_t stream) {
  const float* proj = (const float*)d_in[0];
  const float* hctc = (const float*)d_in[1];
  const float* A = (const float*)d_in[2];
  const int* spikes = (const int*)d_in[3];
  const float* Wmem = (const float*)d_in[4];
  const float* bmem = (const float*)d_in[5];
  const float* Wkv = (const float*)d_in[6];
  const float* bkv = (const float*)d_in[7];
  const float* Wq = (const float*)d_in[8];
  const float* bq = (const float*)d_in[9];
  const float* Wqkv = (const float*)d_in[10];
  const float* bqkv = (const float*)d_in[11];
  const float* Watt = (const float*)d_in[12];
  const float* batt = (const float*)d_in[13];
  const float* Wo = (const float*)d_in[14];
  const float* bo = (const float*)d_in[15];
  float* out = (float*)d_out;
  (void)in_sizes; (void)n_in; (void)out_size; (void)ws_size;

  char* w = (char*)d_ws;
  bf16* projb = (bf16*)(w + 0);            //  67108864 B
  bf16* kvb   = (bf16*)(w + 67108864);     // 134217728 B
  bf16* w2t   = (bf16*)(w + 201326592);    //   1048576 B
  float* b2   = (float*)(w + 202375168);   //      4096 B
  int* spk    = (int*)(w + 202379264);     //      3072 B
  float* warr = (float*)(w + 202382336);   //     52224 B
  float* winv = (float*)(w + 202434560);   //      3072 B
  float* gk   = (float*)(w + 202437632);   //      3072 B
  float* Zb   = (float*)(w + 202440704);   //   1572864 B
  float* qws  = (float*)(w + 204013568);   //   1572864 B
  float* pm   = (float*)(w + 205586432);   //    196608 B
  float* pl   = (float*)(w + 205783040);   //    196608 B
  float* pu   = (float*)(w + 205979648);   //  12582912 B -> end 218562560
  // wtHi/wtLo ALIAS the projb region (dead after kv_gemm; prep_wt runs after)
  short* wtHi = (short*)(w + 0);           //   3670016 B (aliases projb)
  short* wtLo = (short*)(w + 3670016);     //   3670016 B (aliases projb)

  prep_w2t<<<dim3(16, 8), 256, 0, stream>>>(Wmem, Wqkv, w2t);
  bias2_kernel<<<16, 256, 0, stream>>>(bmem, Wqkv, bqkv, b2);
  cvt_bf16<<<16384, 256, 0, stream>>>(proj, projb);
  kv_gemm<<<dim3(8, 512), 256, 0, stream>>>(projb, w2t, b2, kvb);
  prep_wt<<<dim3(8, 8, 7), 256, 0, stream>>>(Wkv, Wq, Wqkv, Watt, Wo, wtHi, wtLo);
  topk_kernel<<<24, 128, 0, stream>>>(A, spikes, spk, warr, winv, gk);
  z_gather<<<768, 256, 0, stream>>>(hctc, spk, warr, winv, Zb);
  seed_mfma<<<48, 512, 0, stream>>>(Zb, wtHi, wtLo, bkv, bq, bqkv, qws);
  attn_kernel<<<512, 256, 0, stream>>>(kvb, qws, pm, pl, pu);
  out_mfma<<<48, 512, 0, stream>>>(pm, pl, pu, wtHi, wtLo, batt, bo, gk, out);
}